// Round 11
// baseline (169.324 us; speedup 1.0000x reference)
//
#include <hip/hip_runtime.h>
#include <stdint.h>

// ---------------------------------------------------------------------------
// SelfAttention: B=8,S=1024,D=1024,H=16,HD=64
//   Y{q,k,v} = bf16(X) @ bf16(W)^T (fused fp32->bf16 in staging), then
//   flash attention (swapped QK^T, in-register softmax, O^T accumulation).
// Round 11:
//  - gemm: 128x128 tiles, 256 thr / 4 waves, 64 KB LDS -> 2 INDEPENDENT
//    blocks per CU (was 1 block of 8 barrier-locked waves at 96 KB). When
//    one block drains vmcnt/barrier, the other block's waves fill the
//    MFMA/LDS pipes (m114 mechanism). 1536 blocks = 3 exact rounds.
//    Same fused-convert reg-staging schedule and swizzle as R8.
//  - attn: exact R8 version (best measured; R9/R10 attn experiments were
//    neutral-to-negative and are reverted).
// ws layout: Ybf only: 3 * 8192*1024 bf16 = 50,331,648 bytes.
// ---------------------------------------------------------------------------

#define B_N 8
#define S_N 1024
#define D_N 1024
#define H_N 16
#define HD_N 64
#define M_N (B_N * S_N) /* 8192 */

typedef __bf16 bfrag __attribute__((ext_vector_type(8)));
typedef float f32x4 __attribute__((ext_vector_type(4)));
typedef float f32x16 __attribute__((ext_vector_type(16)));
typedef unsigned int u32;
typedef u32 u32x2 __attribute__((ext_vector_type(2)));
typedef u32 u32x4 __attribute__((ext_vector_type(4)));
typedef unsigned short u16;

__device__ __forceinline__ u16 f2bf(float f) {  // RNE fp32 -> bf16 bits
  uint32_t u = __float_as_uint(f);
  u += 0x7FFFu + ((u >> 16) & 1u);
  return (u16)(u >> 16);
}

__device__ __forceinline__ void gl_lds16(const void* g, void* l) {
  __builtin_amdgcn_global_load_lds(
      (const __attribute__((address_space(1))) uint32_t*)g,
      (__attribute__((address_space(3))) uint32_t*)l, 16, 0, 0);
}

__device__ __forceinline__ u32 cvtpk(float lo, float hi) {
  u32 r;
  asm("v_cvt_pk_bf16_f32 %0, %1, %2" : "=v"(r) : "v"(lo), "v"(hi));
  return r;
}

__device__ __forceinline__ float exp2r(float x) {  // raw v_exp_f32
#if __has_builtin(__builtin_amdgcn_exp2f)
  return __builtin_amdgcn_exp2f(x);
#else
  float r;
  asm("v_exp_f32 %0, %1" : "=v"(r) : "v"(x));
  return r;
#endif
}

__device__ __forceinline__ u32x2 pl32swap(u32 a, u32 b) {
#if __has_builtin(__builtin_amdgcn_permlane32_swap)
  return __builtin_amdgcn_permlane32_swap(a, b, false, false);
#else
  u32 sa = (u32)__shfl_xor((int)a, 32, 64), sb = (u32)__shfl_xor((int)b, 32, 64);
  const bool hi = (threadIdx.x & 32) != 0;
  u32x2 r;
  r[0] = hi ? sb : a;
  r[1] = hi ? b : sa;
  return r;
#endif
}

__device__ __forceinline__ float xhalf_max(float v) {
  u32x2 r = pl32swap(__float_as_uint(v), __float_as_uint(v));
  return fmaxf(__uint_as_float(r[0]), __uint_as_float(r[1]));
}
__device__ __forceinline__ float xhalf_add(float v) {
  u32x2 r = pl32swap(__float_as_uint(v), __float_as_uint(v));
  return __uint_as_float(r[0]) + __uint_as_float(r[1]);
}

// ---------------- fused projection GEMM: Y = bf16(X) @ bf16(W)^T -----------
// 128x128 tiles, 1536 blocks = 3 exact rounds at 2 blocks/CU, 4 waves 2Mx2N,
// 2-buffer LDS (64 KB). R8 wait schedule; inter-block overlap hides drains.
__global__ __launch_bounds__(256, 2) void gemm_qkv(
    const float* __restrict__ Qs, const float* __restrict__ Ks,
    const float* __restrict__ Vs, const float* __restrict__ WQ,
    const float* __restrict__ WK, const float* __restrict__ WV,
    u16* __restrict__ Ybf) {
  const int bid = blockIdx.x;
  const int wid = (bid & 7) * 192 + (bid >> 3);  // bijective: 1536 % 8 == 0
  const int mat = wid >> 9;                      // 512 tiles per matrix
  const int rem = wid & 511;
  const int m0 = (rem >> 3) * 128;
  const int n0 = (rem & 7) * 128;

  const float* A = mat == 0 ? Qs : (mat == 1 ? Ks : Vs);
  const float* Bw = mat == 0 ? WQ : (mat == 1 ? WK : WV);
  u16* Y = Ybf + (size_t)mat * (M_N * D_N);

  __shared__ u16 Ast[2][2][4096];  // [buf][chunk: 64 rows][64x64], 32 KB
  __shared__ u16 Bst[2][2][4096];  // [buf][chunk: 64 cols][64x64], 32 KB

  const int t = threadIdx.x;
  const int w = t >> 6, l = t & 63;
  const int lr = l & 15, lg = l >> 4;
  const int wm = w >> 1, wn = w & 1;

  // staging: thread t owns row t>>2, 16-col slot (t&3)*16 of each 64x64 chunk
  const int srow = t >> 2, scol = (t & 3) * 16;
  const float* aSrc = A + (size_t)(m0 + srow) * D_N + scol;
  const float* bSrc = Bw + (size_t)(n0 + srow) * D_N + scol;
  // swizzled ds_write dest: two 16B units u = (t&3)*2 + j, dest = u^(row&7)
  const int su = (t & 3) * 2;
  const int dstw0 = srow * 64 + ((su ^ (srow & 7)) << 3);
  const int dstw1 = srow * 64 + (((su + 1) ^ (srow & 7)) << 3);

  // swizzled ds_read column offsets (u16 units): unit (kk*4+lg) ^ (lr&7)
  const int asw = (lr & 7) << 3;
  const int koff0 = (lg * 8) ^ asw;
  const int koff1 = (32 + lg * 8) ^ asw;

  float4 ra[2][4], rw[2][4];

#define LOADT(tt)                                                             \
  do {                                                                        \
    _Pragma("unroll") for (int c_ = 0; c_ < 2; ++c_) {                        \
      const float* pa_ = aSrc + (size_t)(c_ * 64) * D_N + (tt)*64;            \
      const float* pb_ = bSrc + (size_t)(c_ * 64) * D_N + (tt)*64;            \
      _Pragma("unroll") for (int j_ = 0; j_ < 4; ++j_) {                      \
        ra[c_][j_] = *(const float4*)(pa_ + j_ * 4);                          \
        rw[c_][j_] = *(const float4*)(pb_ + j_ * 4);                          \
      }                                                                       \
    }                                                                         \
  } while (0)
#define WRITET(buf)                                                           \
  do {                                                                        \
    _Pragma("unroll") for (int c_ = 0; c_ < 2; ++c_) {                        \
      u32x4 p0_, p1_;                                                         \
      p0_[0] = cvtpk(ra[c_][0].x, ra[c_][0].y);                               \
      p0_[1] = cvtpk(ra[c_][0].z, ra[c_][0].w);                               \
      p0_[2] = cvtpk(ra[c_][1].x, ra[c_][1].y);                               \
      p0_[3] = cvtpk(ra[c_][1].z, ra[c_][1].w);                               \
      p1_[0] = cvtpk(ra[c_][2].x, ra[c_][2].y);                               \
      p1_[1] = cvtpk(ra[c_][2].z, ra[c_][2].w);                               \
      p1_[2] = cvtpk(ra[c_][3].x, ra[c_][3].y);                               \
      p1_[3] = cvtpk(ra[c_][3].z, ra[c_][3].w);                               \
      *(u32x4*)(&Ast[buf][c_][dstw0]) = p0_;                                  \
      *(u32x4*)(&Ast[buf][c_][dstw1]) = p1_;                                  \
      p0_[0] = cvtpk(rw[c_][0].x, rw[c_][0].y);                               \
      p0_[1] = cvtpk(rw[c_][0].z, rw[c_][0].w);                               \
      p0_[2] = cvtpk(rw[c_][1].x, rw[c_][1].y);                               \
      p0_[3] = cvtpk(rw[c_][1].z, rw[c_][1].w);                               \
      p1_[0] = cvtpk(rw[c_][2].x, rw[c_][2].y);                               \
      p1_[1] = cvtpk(rw[c_][2].z, rw[c_][2].w);                               \
      p1_[2] = cvtpk(rw[c_][3].x, rw[c_][3].y);                               \
      p1_[3] = cvtpk(rw[c_][3].z, rw[c_][3].w);                               \
      *(u32x4*)(&Bst[buf][c_][dstw0]) = p0_;                                  \
      *(u32x4*)(&Bst[buf][c_][dstw1]) = p1_;                                  \
    }                                                                         \
  } while (0)
#define LDA8(AR, buf)                                                         \
  do {                                                                        \
    const u16* p_ = &Ast[buf][wm][lr * 64];                                   \
    _Pragma("unroll") for (int mf_ = 0; mf_ < 4; ++mf_) {                     \
      AR[mf_][0] = *(const bfrag*)(p_ + mf_ * 1024 + koff0);                  \
      AR[mf_][1] = *(const bfrag*)(p_ + mf_ * 1024 + koff1);                  \
    }                                                                         \
  } while (0)
#define LDB4(BR, buf, h)                                                      \
  do {                                                                        \
    const u16* p_ = &Bst[buf][wn][((h)*32 + lr) * 64];                        \
    BR[0][0] = *(const bfrag*)(p_ + koff0);                                   \
    BR[0][1] = *(const bfrag*)(p_ + koff1);                                   \
    BR[1][0] = *(const bfrag*)(p_ + 1024 + koff0);                            \
    BR[1][1] = *(const bfrag*)(p_ + 1024 + koff1);                            \
  } while (0)
#define MMAH(h, AR, BR)                                                       \
  do {                                                                        \
    __builtin_amdgcn_s_setprio(1);                                            \
    _Pragma("unroll") for (int mf_ = 0; mf_ < 4; ++mf_)                       \
    _Pragma("unroll") for (int j_ = 0; j_ < 2; ++j_)                          \
    _Pragma("unroll") for (int kk_ = 0; kk_ < 2; ++kk_)                       \
      acc[mf_][(h)*2 + j_] = __builtin_amdgcn_mfma_f32_16x16x32_bf16(         \
          AR[mf_][kk_], BR[j_][kk_], acc[mf_][(h)*2 + j_], 0, 0, 0);          \
    __builtin_amdgcn_s_setprio(0);                                            \
  } while (0)
#define BARR()                                                                \
  __builtin_amdgcn_s_barrier();                                               \
  __builtin_amdgcn_sched_barrier(0)
#define WAITL()                                                               \
  asm volatile("s_waitcnt lgkmcnt(0)" ::: "memory");                          \
  __builtin_amdgcn_sched_barrier(0)
#define WAITV0()                                                              \
  asm volatile("s_waitcnt vmcnt(0)" ::: "memory");                            \
  __builtin_amdgcn_sched_barrier(0)

  f32x4 acc[4][4];
#pragma unroll
  for (int i = 0; i < 4; ++i)
#pragma unroll
    for (int j = 0; j < 4; ++j) acc[i][j] = (f32x4){0.f, 0.f, 0.f, 0.f};

  // prologue: tile0 load->write; tile1 loads in flight
  LOADT(0);
  WAITV0();
  WRITET(0);
  LOADT(1);
  WAITL();
  BARR();

  for (int kt = 0; kt < 16; ++kt) {
    const int cb = kt & 1;
    bfrag a[4][2], b[2][2];
    LDA8(a, cb);
    LDB4(b, cb, 0);
    if (kt < 15) {
      WAITV0();          // tile kt+1 loads (issued during kt-1) done
      WRITET(cb ^ 1);    // buffer cb^1 freed by kt-1's end barrier
      if (kt < 14) LOADT(kt + 2);
    }
    WAITL();             // frag reads + ds_writes drained
    MMAH(0, a, b);
    LDB4(b, cb, 1);
    WAITL();
    MMAH(1, a, b);
    BARR();              // publish writes; free buffer cb
  }

  // ---- epilogue ----
  const float alpha = (mat == 0) ? 0.18033688011112042f : 1.0f;
  const int mrow = m0 + wm * 64;
  const int ncol = n0 + wn * 64;
  if (mat < 2) {
#pragma unroll
    for (int mf = 0; mf < 4; ++mf) {
      const int row0 = mrow + mf * 16 + lg * 4;
#pragma unroll
      for (int nf = 0; nf < 4; ++nf) {
        const int col = ncol + nf * 16 + lr;
#pragma unroll
        for (int r = 0; r < 4; ++r)
          Y[(size_t)(row0 + r) * D_N + col] = f2bf(acc[mf][nf][r] * alpha);
      }
    }
  } else {
    const int b = m0 >> 10;
#pragma unroll
    for (int mf = 0; mf < 4; ++mf) {
      const int s0 = (m0 & 1023) + wm * 64 + mf * 16 + lg * 4;
#pragma unroll
      for (int nf = 0; nf < 4; ++nf) {
        const int col = ncol + nf * 16 + lr;
        const f32x4 v = acc[mf][nf];
        ushort4 pk;
        pk.x = f2bf(v[0]); pk.y = f2bf(v[1]);
        pk.z = f2bf(v[2]); pk.w = f2bf(v[3]);
        *(ushort4*)(Y + (size_t)(b * D_N + col) * S_N + s0) = pk;
      }
    }
  }
#undef LOADT
#undef WRITET
#undef LDA8
#undef LDB4
#undef MMAH
#undef BARR
#undef WAITL
#undef WAITV0
}

// ---------------- flash attention (R8: tri-buffered LDS K/V, vmcnt(4)) -----
union AttnSMem {
  struct { u16 K[3][4096]; u16 V[3][4096]; } st;  // 48 KB, triple-buffered
  float ol[4][32 * 34];                           // epilogue transpose (17 KB)
};

__global__ __launch_bounds__(256, 3) void attn_fwd(const u16* __restrict__ Yq,
                                                   const u16* __restrict__ Yk,
                                                   const u16* __restrict__ Yv,
                                                   float* __restrict__ out) {
  // XCD-chunked work id: 1024 blocks, 8 XCDs, 128 consecutive ids per XCD
  const int bid = blockIdx.x;
  const int wid = (bid & 7) * 128 + (bid >> 3);
  const int qt = wid & 7, bh = wid >> 3;
  const int b = bh >> 4, h = bh & 15;
  const int t = threadIdx.x, w = t >> 6, l = t & 63;
  const int ln = l & 31, hi = l >> 5;

  __shared__ AttnSMem sm;

  const int qbase = qt * 128 + w * 32;

  // ---- staging constants (pre-swizzled global source, rule 21) ----
  const int row0 = w * 8 + (l >> 3);
  const int srcoff = (((l & 7) ^ ((l >> 3) & 7)) << 3);
  const u16* kS0 = Yk + ((size_t)(b * S_N + row0) * D_N + h * HD_N + srcoff);
  const u16* vS0 = Yv + ((size_t)(b * D_N + h * HD_N + row0) * S_N + srcoff);

#define STAGE(buf, tt)                                                        \
  do {                                                                        \
    const u16* ka_ = kS0 + (size_t)(tt) * 64 * D_N;                           \
    const u16* va_ = vS0 + (tt) * 64;                                         \
    gl_lds16(ka_, sm.st.K[buf] + w * 512);                                    \
    gl_lds16(ka_ + (size_t)32 * D_N, sm.st.K[buf] + 2048 + w * 512);          \
    gl_lds16(va_, sm.st.V[buf] + w * 512);                                    \
    gl_lds16(va_ + (size_t)32 * S_N, sm.st.V[buf] + 2048 + w * 512);          \
  } while (0)

  // Q loads FIRST (oldest in the vm queue)
  bfrag qf[4];
  {
    const u16* qp = Yq + ((size_t)(b * S_N + qbase + ln) * D_N + h * HD_N + hi * 8);
#pragma unroll
    for (int c = 0; c < 4; ++c) qf[c] = *(const bfrag*)(qp + c * 16);
  }

  // prologue: stage tiles 0 and 1
  STAGE(0, 0);
  STAGE(1, 1);

  int kcol[4];
#pragma unroll
  for (int c = 0; c < 4; ++c)
    kcol[c] = (((c * 32 + hi * 16) ^ ((ln & 7) << 4)) >> 1);

  f32x16 o0, o1;
#pragma unroll
  for (int r = 0; r < 16; ++r) { o0[r] = 0.f; o1[r] = 0.f; }
  float m_r = -3.0e38f, l_r = 0.f;

  asm volatile("s_waitcnt vmcnt(4)" ::: "memory");
  __builtin_amdgcn_sched_barrier(0);
  __builtin_amdgcn_s_barrier();

  int rd = 0, sb = 2;  // read buffer kt%3; stage buffer (kt+2)%3
  for (int kt = 0; kt < 16; ++kt) {
    if (kt < 14) STAGE(sb, kt + 2);

    const u16* Kb = sm.st.K[rd];
    const u16* Vb = sm.st.V[rd];

    bfrag kf[8];
#pragma unroll
    for (int s2 = 0; s2 < 2; ++s2)
#pragma unroll
      for (int c = 0; c < 4; ++c)
        kf[s2 * 4 + c] = *(const bfrag*)(Kb + (s2 * 32 + ln) * 64 + kcol[c]);

    f32x16 sa, sbv;
#pragma unroll
    for (int r = 0; r < 16; ++r) { sa[r] = 0.f; sbv[r] = 0.f; }
    __builtin_amdgcn_s_setprio(1);
#pragma unroll
    for (int c = 0; c < 4; ++c) {
      sa = __builtin_amdgcn_mfma_f32_32x32x16_bf16(kf[c], qf[c], sa, 0, 0, 0);
      sbv = __builtin_amdgcn_mfma_f32_32x32x16_bf16(kf[4 + c], qf[c], sbv, 0, 0, 0);
    }
    __builtin_amdgcn_s_setprio(0);

    bfrag vf[8];
#pragma unroll
    for (int hf = 0; hf < 2; ++hf)
#pragma unroll
      for (int c = 0; c < 4; ++c)
        vf[hf * 4 + c] = *(const bfrag*)(Vb + (hf * 32 + ln) * 64 + kcol[c]);

    // ---- online softmax, in-lane, tree reductions ----
    float t16[16];
#pragma unroll
    for (int r = 0; r < 16; ++r) t16[r] = fmaxf(sa[r], sbv[r]);
    float t8[8];
#pragma unroll
    for (int r = 0; r < 8; ++r) t8[r] = fmaxf(t16[r], t16[r + 8]);
    float t4[4];
#pragma unroll
    for (int r = 0; r < 4; ++r) t4[r] = fmaxf(t8[r], t8[r + 4]);
    float pmax = fmaxf(fmaxf(t4[0], t4[1]), fmaxf(t4[2], t4[3]));
    pmax = xhalf_max(pmax);

    if (__any(pmax > m_r + 8.f)) {  // defer-max (T13)
      const float mnew = fmaxf(m_r, pmax);
      const float corr = exp2r(m_r - mnew);
#pragma unroll
      for (int r = 0; r < 16; ++r) { o0[r] *= corr; o1[r] *= corr; }
      l_r *= corr;
      m_r = mnew;
    }

#pragma unroll
    for (int r = 0; r < 16; ++r) sa[r] = exp2r(sa[r] - m_r);
#pragma unroll
    for (int r = 0; r < 16; ++r) sbv[r] = exp2r(sbv[r] - m_r);
    float s16[16];
#pragma unroll
    for (int r = 0; r < 16; ++r) s16[r] = sa[r] + sbv[r];
    float s8[8];
#pragma unroll
    for (int r = 0; r < 8; ++r) s8[r] = s16[r] + s16[r + 8];
    float s4[4];
#pragma unroll
    for (int r = 0; r < 4; ++r) s4[r] = s8[r] + s8[r + 4];
    float rsum = (s4[0] + s4[1]) + (s4[2] + s4[3]);
    l_r += xhalf_add(rsum);

    // ---- pack P to bf16 (cvt_pk + permlane32_swap) + PV ----
    __builtin_amdgcn_s_setprio(1);
#pragma unroll
    for (int c = 0; c < 4; ++c) {
      const int bs = (c & 1) * 8;
      float p0, p1, p2, p3, p4, p5, p6, p7;
      if (c < 2) {
        p0 = sa[bs + 0]; p1 = sa[bs + 1]; p2 = sa[bs + 2]; p3 = sa[bs + 3];
        p4 = sa[bs + 4]; p5 = sa[bs + 5]; p6 = sa[bs + 6]; p7 = sa[bs + 7];
      } else {
        p0 = sbv[bs + 0]; p1 = sbv[bs + 1]; p2 = sbv[bs + 2]; p3 = sbv[bs + 3];
        p4 = sbv[bs + 4]; p5 = sbv[bs + 5]; p6 = sbv[bs + 6]; p7 = sbv[bs + 7];
      }
      const u32 x1 = cvtpk(p0, p1), x2 = cvtpk(p2, p3);
      const u32 y1 = cvtpk(p4, p5), y2 = cvtpk(p6, p7);
      const u32x2 s1 = pl32swap(x1, y1);
      const u32x2 s2 = pl32swap(x2, y2);
      union { u32 u[4]; bfrag v; } pu;
      pu.u[0] = s1[0]; pu.u[1] = s2[0]; pu.u[2] = s1[1]; pu.u[3] = s2[1];
      o0 = __builtin_amdgcn_mfma_f32_32x32x16_bf16(vf[c], pu.v, o0, 0, 0, 0);
      o1 = __builtin_amdgcn_mfma_f32_32x32x16_bf16(vf[4 + c], pu.v, o1, 0, 0, 0);
    }
    __builtin_amdgcn_s_setprio(0);

    if (kt < 14) {
      asm volatile("s_waitcnt vmcnt(4)" ::: "memory");
    } else {
      asm volatile("s_waitcnt vmcnt(0)" ::: "memory");
    }
    __builtin_amdgcn_sched_barrier(0);
    __builtin_amdgcn_s_barrier();

    rd = (rd == 2) ? 0 : rd + 1;
    sb = (sb == 2) ? 0 : sb + 1;
  }

  // ---- epilogue: normalize, transpose O^T -> O via LDS (2 half-passes) ----
  const float inv = 1.f / l_r;
  float* ow = sm.ol[w];
  const int qr = l >> 1, ch = l & 1;
  const float* rp = ow + qr * 34 + ch * 16;
  float* op = out + ((size_t)(b * S_N + qbase + qr) * D_N + h * HD_N + ch * 16);

#pragma unroll
  for (int g = 0; g < 4; ++g) {
    f32x4 v;
#pragma unroll
    for (int j = 0; j < 4; ++j) v[j] = o0[g * 4 + j] * inv;
    *(f32x4*)(ow + ln * 34 + g * 8 + hi * 4) = v;
  }
  asm volatile("s_waitcnt lgkmcnt(0)" ::: "memory");
  __builtin_amdgcn_sched_barrier(0);
#pragma unroll
  for (int j = 0; j < 4; ++j)
    *(f32x4*)(op + j * 4) = *(const f32x4*)(rp + j * 4);
  asm volatile("s_waitcnt lgkmcnt(0)" ::: "memory");
  __builtin_amdgcn_sched_barrier(0);

#pragma unroll
  for (int g = 0; g < 4; ++g) {
    f32x4 v;
#pragma unroll
    for (int j = 0; j < 4; ++j) v[j] = o1[g * 4 + j] * inv;
    *(f32x4*)(ow + ln * 34 + g * 8 + hi * 4) = v;
  }
  asm volatile("s_waitcnt lgkmcnt(0)" ::: "memory");
  __builtin_amdgcn_sched_barrier(0);
#pragma unroll
  for (int j = 0; j < 4; ++j)
    *(f32x4*)(op + 32 + j * 4) = *(const f32x4*)(rp + j * 4);
#undef STAGE
}

// ---------------------------------------------------------------------------
extern "C" void kernel_launch(void* const* d_in, const int* in_sizes, int n_in,
                              void* d_out, int out_size, void* d_ws, size_t ws_size,
                              hipStream_t stream) {
  const float* Qs = (const float*)d_in[0];
  const float* Ks = (const float*)d_in[1];
  const float* Vs = (const float*)d_in[2];
  const float* WQ = (const float*)d_in[3];
  const float* WK = (const float*)d_in[4];
  const float* WV = (const float*)d_in[5];
  if (ws_size < 50331648ull) return;  // Ybf: 3 * 8192*1024 bf16

  u16* Ybf = (u16*)d_ws;
  float* out = (float*)d_out;

  gemm_qkv<<<dim3(1536), 256, 0, stream>>>(Qs, Ks, Vs, WQ, WK, WV, Ybf);
  attn_fwd<<<dim3(1024), 256, 0, stream>>>(Ybf, Ybf + 8388608, Ybf + 16777216, out);
}

// Round 12
// 148.095 us; speedup vs baseline: 1.1433x; 1.1433x over previous
//
#include <hip/hip_runtime.h>
#include <stdint.h>

// ---------------------------------------------------------------------------
// SelfAttention: B=8,S=1024,D=1024,H=16,HD=64
//   Y{q,k,v} = bf16(X) @ bf16(W)^T (fused fp32->bf16 in staging), then
//   flash attention (swapped QK^T, in-register softmax, O^T accumulation).
// Round 12:
//  - gemm: R8 schedule (measured best) + both B-half fragment reads issued
//    upfront (one lgkm drain instead of two; reads overlap WRITET issue).
//  - attn: 8 waves/block (512 thr, 256 q-rows), 512 blocks. Staging per
//    tile = 2 gl_lds/thread (was 4): 8 waves cooperatively fill 8KB K +
//    8KB V. Counted-vmcnt ledger halves: prologue vmcnt(2) retires
//    Q+tile0; loop vmcnt(2) retires kt+1; tail vmcnt(0). Tri-buffer 48KB.
// ws layout: Ybf only: 3 * 8192*1024 bf16 = 50,331,648 bytes.
// ---------------------------------------------------------------------------

#define B_N 8
#define S_N 1024
#define D_N 1024
#define H_N 16
#define HD_N 64
#define M_N (B_N * S_N) /* 8192 */

typedef __bf16 bfrag __attribute__((ext_vector_type(8)));
typedef float f32x4 __attribute__((ext_vector_type(4)));
typedef float f32x16 __attribute__((ext_vector_type(16)));
typedef unsigned int u32;
typedef u32 u32x2 __attribute__((ext_vector_type(2)));
typedef u32 u32x4 __attribute__((ext_vector_type(4)));
typedef unsigned short u16;

__device__ __forceinline__ u16 f2bf(float f) {  // RNE fp32 -> bf16 bits
  uint32_t u = __float_as_uint(f);
  u += 0x7FFFu + ((u >> 16) & 1u);
  return (u16)(u >> 16);
}

__device__ __forceinline__ void gl_lds16(const void* g, void* l) {
  __builtin_amdgcn_global_load_lds(
      (const __attribute__((address_space(1))) uint32_t*)g,
      (__attribute__((address_space(3))) uint32_t*)l, 16, 0, 0);
}

__device__ __forceinline__ u32 cvtpk(float lo, float hi) {
  u32 r;
  asm("v_cvt_pk_bf16_f32 %0, %1, %2" : "=v"(r) : "v"(lo), "v"(hi));
  return r;
}

__device__ __forceinline__ float exp2r(float x) {  // raw v_exp_f32
#if __has_builtin(__builtin_amdgcn_exp2f)
  return __builtin_amdgcn_exp2f(x);
#else
  float r;
  asm("v_exp_f32 %0, %1" : "=v"(r) : "v"(x));
  return r;
#endif
}

__device__ __forceinline__ u32x2 pl32swap(u32 a, u32 b) {
#if __has_builtin(__builtin_amdgcn_permlane32_swap)
  return __builtin_amdgcn_permlane32_swap(a, b, false, false);
#else
  u32 sa = (u32)__shfl_xor((int)a, 32, 64), sb = (u32)__shfl_xor((int)b, 32, 64);
  const bool hi = (threadIdx.x & 32) != 0;
  u32x2 r;
  r[0] = hi ? sb : a;
  r[1] = hi ? b : sa;
  return r;
#endif
}

__device__ __forceinline__ float xhalf_max(float v) {
  u32x2 r = pl32swap(__float_as_uint(v), __float_as_uint(v));
  return fmaxf(__uint_as_float(r[0]), __uint_as_float(r[1]));
}
__device__ __forceinline__ float xhalf_add(float v) {
  u32x2 r = pl32swap(__float_as_uint(v), __float_as_uint(v));
  return __uint_as_float(r[0]) + __uint_as_float(r[1]);
}

// ---------------- fused projection GEMM: Y = bf16(X) @ bf16(W)^T -----------
// 256x128 tiles, 768 blocks = 3 exact rounds, 8 waves 4Mx2N, 2-buffer LDS.
// R8 wait schedule; B-half-1 frag reads hoisted before the drain.
__global__ __launch_bounds__(512, 1) void gemm_qkv(
    const float* __restrict__ Qs, const float* __restrict__ Ks,
    const float* __restrict__ Vs, const float* __restrict__ WQ,
    const float* __restrict__ WK, const float* __restrict__ WV,
    u16* __restrict__ Ybf) {
  const int bid = blockIdx.x;
  const int wid = (bid & 7) * 96 + (bid >> 3);  // bijective: 768 % 8 == 0
  const int mat = wid >> 8;                     // 256 tiles per matrix
  const int rem = wid & 255;
  const int m0 = (rem >> 3) * 256;
  const int n0 = (rem & 7) * 128;

  const float* A = mat == 0 ? Qs : (mat == 1 ? Ks : Vs);
  const float* Bw = mat == 0 ? WQ : (mat == 1 ? WK : WV);
  u16* Y = Ybf + (size_t)mat * (M_N * D_N);

  __shared__ u16 Ast[2][4][4096];  // [buf][chunk: 64 rows][64x64], 64 KB
  __shared__ u16 Bst[2][2][4096];  // [buf][chunk: 64 cols][64x64], 32 KB

  const int t = threadIdx.x;
  const int w = t >> 6, l = t & 63;
  const int lr = l & 15, lg = l >> 4;
  const int wm = w >> 1, wn = w & 1;

  const float* aSrc = A + (size_t)(m0 + (t >> 3)) * D_N + (t & 7) * 8;
  const float* bSrc = Bw + (size_t)(n0 + (t >> 3)) * D_N + (t & 7) * 8;
  const int dst8 = (t >> 3) * 64 + ((((t & 7) ^ ((t >> 3) & 7))) << 3);

  const int asw = (lr & 7) << 3;
  const int koff0 = (lg * 8) ^ asw;
  const int koff1 = (32 + lg * 8) ^ asw;

  float4 ra[4][2], rw[2][2];

#define LOADT(tt)                                                             \
  do {                                                                        \
    _Pragma("unroll") for (int c_ = 0; c_ < 4; ++c_) {                        \
      ra[c_][0] = *(const float4*)(aSrc + (size_t)(c_ * 64) * D_N + (tt)*64); \
      ra[c_][1] =                                                             \
          *(const float4*)(aSrc + (size_t)(c_ * 64) * D_N + (tt)*64 + 4);     \
    }                                                                         \
    _Pragma("unroll") for (int c_ = 0; c_ < 2; ++c_) {                        \
      rw[c_][0] = *(const float4*)(bSrc + (size_t)(c_ * 64) * D_N + (tt)*64); \
      rw[c_][1] =                                                             \
          *(const float4*)(bSrc + (size_t)(c_ * 64) * D_N + (tt)*64 + 4);     \
    }                                                                         \
  } while (0)
#define WRITET(buf)                                                           \
  do {                                                                        \
    _Pragma("unroll") for (int c_ = 0; c_ < 4; ++c_) {                        \
      u32x4 pk_;                                                              \
      pk_[0] = cvtpk(ra[c_][0].x, ra[c_][0].y);                               \
      pk_[1] = cvtpk(ra[c_][0].z, ra[c_][0].w);                               \
      pk_[2] = cvtpk(ra[c_][1].x, ra[c_][1].y);                               \
      pk_[3] = cvtpk(ra[c_][1].z, ra[c_][1].w);                               \
      *(u32x4*)(&Ast[buf][c_][dst8]) = pk_;                                   \
    }                                                                         \
    _Pragma("unroll") for (int c_ = 0; c_ < 2; ++c_) {                        \
      u32x4 pk_;                                                              \
      pk_[0] = cvtpk(rw[c_][0].x, rw[c_][0].y);                               \
      pk_[1] = cvtpk(rw[c_][0].z, rw[c_][0].w);                               \
      pk_[2] = cvtpk(rw[c_][1].x, rw[c_][1].y);                               \
      pk_[3] = cvtpk(rw[c_][1].z, rw[c_][1].w);                               \
      *(u32x4*)(&Bst[buf][c_][dst8]) = pk_;                                   \
    }                                                                         \
  } while (0)
#define LDA8(AR, buf)                                                         \
  do {                                                                        \
    const u16* p_ = &Ast[buf][wm][lr * 64];                                   \
    _Pragma("unroll") for (int mf_ = 0; mf_ < 4; ++mf_) {                     \
      AR[mf_][0] = *(const bfrag*)(p_ + mf_ * 1024 + koff0);                  \
      AR[mf_][1] = *(const bfrag*)(p_ + mf_ * 1024 + koff1);                  \
    }                                                                         \
  } while (0)
#define LDB4(BR, buf, h)                                                      \
  do {                                                                        \
    const u16* p_ = &Bst[buf][wn][((h)*32 + lr) * 64];                        \
    BR[0][0] = *(const bfrag*)(p_ + koff0);                                   \
    BR[0][1] = *(const bfrag*)(p_ + koff1);                                   \
    BR[1][0] = *(const bfrag*)(p_ + 1024 + koff0);                            \
    BR[1][1] = *(const bfrag*)(p_ + 1024 + koff1);                            \
  } while (0)
#define MMAH(h, AR, BR)                                                       \
  do {                                                                        \
    __builtin_amdgcn_s_setprio(1);                                            \
    _Pragma("unroll") for (int mf_ = 0; mf_ < 4; ++mf_)                       \
    _Pragma("unroll") for (int j_ = 0; j_ < 2; ++j_)                          \
    _Pragma("unroll") for (int kk_ = 0; kk_ < 2; ++kk_)                       \
      acc[mf_][(h)*2 + j_] = __builtin_amdgcn_mfma_f32_16x16x32_bf16(         \
          AR[mf_][kk_], BR[j_][kk_], acc[mf_][(h)*2 + j_], 0, 0, 0);          \
    __builtin_amdgcn_s_setprio(0);                                            \
  } while (0)
#define BARR()                                                                \
  __builtin_amdgcn_s_barrier();                                               \
  __builtin_amdgcn_sched_barrier(0)
#define WAITL()                                                               \
  asm volatile("s_waitcnt lgkmcnt(0)" ::: "memory");                          \
  __builtin_amdgcn_sched_barrier(0)
#define WAITV0()                                                              \
  asm volatile("s_waitcnt vmcnt(0)" ::: "memory");                            \
  __builtin_amdgcn_sched_barrier(0)

  f32x4 acc[4][4];
#pragma unroll
  for (int i = 0; i < 4; ++i)
#pragma unroll
    for (int j = 0; j < 4; ++j) acc[i][j] = (f32x4){0.f, 0.f, 0.f, 0.f};

  // prologue: tile0 load->write; tile1 loads in flight
  LOADT(0);
  WAITV0();
  WRITET(0);
  LOADT(1);
  WAITL();
  BARR();

  for (int kt = 0; kt < 16; ++kt) {
    const int cb = kt & 1;
    bfrag a[4][2], b0[2][2], b1[2][2];
    LDA8(a, cb);
    LDB4(b0, cb, 0);
    LDB4(b1, cb, 1);     // hoisted: all frag reads issued before the drain
    if (kt < 15) {
      WAITV0();          // tile kt+1 loads (issued during kt-1) done
      WRITET(cb ^ 1);    // buffer cb^1 freed by kt-1's end barrier
      if (kt < 14) LOADT(kt + 2);
    }
    WAITL();             // one drain: 24 frag reads + 6 staging writes
    MMAH(0, a, b0);
    MMAH(1, a, b1);
    BARR();              // publish writes; free buffer cb
  }

  // ---- epilogue ----
  const float alpha = (mat == 0) ? 0.18033688011112042f : 1.0f;
  const int mrow = m0 + wm * 64;
  const int ncol = n0 + wn * 64;
  if (mat < 2) {
#pragma unroll
    for (int mf = 0; mf < 4; ++mf) {
      const int row0 = mrow + mf * 16 + lg * 4;
#pragma unroll
      for (int nf = 0; nf < 4; ++nf) {
        const int col = ncol + nf * 16 + lr;
#pragma unroll
        for (int r = 0; r < 4; ++r)
          Y[(size_t)(row0 + r) * D_N + col] = f2bf(acc[mf][nf][r] * alpha);
      }
    }
  } else {
    const int b = m0 >> 10;
#pragma unroll
    for (int mf = 0; mf < 4; ++mf) {
      const int s0 = (m0 & 1023) + wm * 64 + mf * 16 + lg * 4;
#pragma unroll
      for (int nf = 0; nf < 4; ++nf) {
        const int col = ncol + nf * 16 + lr;
        const f32x4 v = acc[mf][nf];
        ushort4 pk;
        pk.x = f2bf(v[0]); pk.y = f2bf(v[1]);
        pk.z = f2bf(v[2]); pk.w = f2bf(v[3]);
        *(ushort4*)(Y + (size_t)(b * D_N + col) * S_N + s0) = pk;
      }
    }
  }
#undef LOADT
#undef WRITET
#undef LDA8
#undef LDB4
#undef MMAH
#undef BARR
#undef WAITL
#undef WAITV0
}

// ---------------- flash attention: 8 waves/block, tri-buffered K/V ---------
union AttnSMem {
  struct { u16 K[3][4096]; u16 V[3][4096]; } st;  // 48 KB, triple-buffered
  float ol[8][32 * 34];                           // epilogue transpose (34.8 KB)
};

__global__ __launch_bounds__(512, 2) void attn_fwd(const u16* __restrict__ Yq,
                                                   const u16* __restrict__ Yk,
                                                   const u16* __restrict__ Yv,
                                                   float* __restrict__ out) {
  // 512 blocks (B*H*4 q-tiles of 256 rows), XCD-chunked (64/XCD)
  const int bid = blockIdx.x;
  const int wid = (bid & 7) * 64 + (bid >> 3);
  const int qt = wid & 3, bh = wid >> 2;
  const int b = bh >> 4, h = bh & 15;
  const int t = threadIdx.x, w = t >> 6, l = t & 63;
  const int ln = l & 31, hi = l >> 5;

  __shared__ AttnSMem sm;

  const int qbase = qt * 256 + w * 32;  // 8 waves x 32 q-rows

  // ---- staging: 512 threads fill one 8KB K-tile + 8KB V-tile per STAGE ----
  // thread t owns row t>>3 (0..63), pre-swizzled source col (rule 21).
  const int row0 = t >> 3;
  const int srcoff = (((t & 7) ^ ((t >> 3) & 7)) << 3);
  const u16* kS0 = Yk + ((size_t)(b * S_N + row0) * D_N + h * HD_N + srcoff);
  const u16* vS0 = Yv + ((size_t)(b * D_N + h * HD_N + row0) * S_N + srcoff);

#define STAGE(buf, tt)                                                        \
  do {                                                                        \
    gl_lds16(kS0 + (size_t)(tt) * 64 * D_N, sm.st.K[buf] + w * 512);          \
    gl_lds16(vS0 + (tt) * 64, sm.st.V[buf] + w * 512);                        \
  } while (0)

  // Q loads FIRST (oldest in the vm queue)
  bfrag qf[4];
  {
    const u16* qp = Yq + ((size_t)(b * S_N + qbase + ln) * D_N + h * HD_N + hi * 8);
#pragma unroll
    for (int c = 0; c < 4; ++c) qf[c] = *(const bfrag*)(qp + c * 16);
  }

  // prologue: stage tiles 0 and 1 (2 loads each per thread)
  STAGE(0, 0);
  STAGE(1, 1);

  int kcol[4];
#pragma unroll
  for (int c = 0; c < 4; ++c)
    kcol[c] = (((c * 32 + hi * 16) ^ ((ln & 7) << 4)) >> 1);

  f32x16 o0, o1;
#pragma unroll
  for (int r = 0; r < 16; ++r) { o0[r] = 0.f; o1[r] = 0.f; }
  float m_r = -3.0e38f, l_r = 0.f;

  // retire Q + tile0 (leaves tile1's 2 loads in flight), publish
  asm volatile("s_waitcnt vmcnt(2)" ::: "memory");
  __builtin_amdgcn_sched_barrier(0);
  __builtin_amdgcn_s_barrier();

  int rd = 0, sb = 2;  // read buffer kt%3; stage buffer (kt+2)%3
  for (int kt = 0; kt < 16; ++kt) {
    if (kt < 14) STAGE(sb, kt + 2);

    const u16* Kb = sm.st.K[rd];
    const u16* Vb = sm.st.V[rd];

    bfrag kf[8];
#pragma unroll
    for (int s2 = 0; s2 < 2; ++s2)
#pragma unroll
      for (int c = 0; c < 4; ++c)
        kf[s2 * 4 + c] = *(const bfrag*)(Kb + (s2 * 32 + ln) * 64 + kcol[c]);

    f32x16 sa, sbv;
#pragma unroll
    for (int r = 0; r < 16; ++r) { sa[r] = 0.f; sbv[r] = 0.f; }
    __builtin_amdgcn_s_setprio(1);
#pragma unroll
    for (int c = 0; c < 4; ++c) {
      sa = __builtin_amdgcn_mfma_f32_32x32x16_bf16(kf[c], qf[c], sa, 0, 0, 0);
      sbv = __builtin_amdgcn_mfma_f32_32x32x16_bf16(kf[4 + c], qf[c], sbv, 0, 0, 0);
    }
    __builtin_amdgcn_s_setprio(0);

    bfrag vf[8];
#pragma unroll
    for (int hf = 0; hf < 2; ++hf)
#pragma unroll
      for (int c = 0; c < 4; ++c)
        vf[hf * 4 + c] = *(const bfrag*)(Vb + (hf * 32 + ln) * 64 + kcol[c]);

    // ---- online softmax, in-lane, tree reductions ----
    float t16[16];
#pragma unroll
    for (int r = 0; r < 16; ++r) t16[r] = fmaxf(sa[r], sbv[r]);
    float t8[8];
#pragma unroll
    for (int r = 0; r < 8; ++r) t8[r] = fmaxf(t16[r], t16[r + 8]);
    float t4[4];
#pragma unroll
    for (int r = 0; r < 4; ++r) t4[r] = fmaxf(t8[r], t8[r + 4]);
    float pmax = fmaxf(fmaxf(t4[0], t4[1]), fmaxf(t4[2], t4[3]));
    pmax = xhalf_max(pmax);

    if (__any(pmax > m_r + 8.f)) {  // defer-max (T13)
      const float mnew = fmaxf(m_r, pmax);
      const float corr = exp2r(m_r - mnew);
#pragma unroll
      for (int r = 0; r < 16; ++r) { o0[r] *= corr; o1[r] *= corr; }
      l_r *= corr;
      m_r = mnew;
    }

#pragma unroll
    for (int r = 0; r < 16; ++r) sa[r] = exp2r(sa[r] - m_r);
#pragma unroll
    for (int r = 0; r < 16; ++r) sbv[r] = exp2r(sbv[r] - m_r);
    float s16[16];
#pragma unroll
    for (int r = 0; r < 16; ++r) s16[r] = sa[r] + sbv[r];
    float s8[8];
#pragma unroll
    for (int r = 0; r < 8; ++r) s8[r] = s16[r] + s16[r + 8];
    float s4[4];
#pragma unroll
    for (int r = 0; r < 4; ++r) s4[r] = s8[r] + s8[r + 4];
    float rsum = (s4[0] + s4[1]) + (s4[2] + s4[3]);
    l_r += xhalf_add(rsum);

    // ---- pack P to bf16 (cvt_pk + permlane32_swap) + PV ----
    __builtin_amdgcn_s_setprio(1);
#pragma unroll
    for (int c = 0; c < 4; ++c) {
      const int bs = (c & 1) * 8;
      float p0, p1, p2, p3, p4, p5, p6, p7;
      if (c < 2) {
        p0 = sa[bs + 0]; p1 = sa[bs + 1]; p2 = sa[bs + 2]; p3 = sa[bs + 3];
        p4 = sa[bs + 4]; p5 = sa[bs + 5]; p6 = sa[bs + 6]; p7 = sa[bs + 7];
      } else {
        p0 = sbv[bs + 0]; p1 = sbv[bs + 1]; p2 = sbv[bs + 2]; p3 = sbv[bs + 3];
        p4 = sbv[bs + 4]; p5 = sbv[bs + 5]; p6 = sbv[bs + 6]; p7 = sbv[bs + 7];
      }
      const u32 x1 = cvtpk(p0, p1), x2 = cvtpk(p2, p3);
      const u32 y1 = cvtpk(p4, p5), y2 = cvtpk(p6, p7);
      const u32x2 s1 = pl32swap(x1, y1);
      const u32x2 s2 = pl32swap(x2, y2);
      union { u32 u[4]; bfrag v; } pu;
      pu.u[0] = s1[0]; pu.u[1] = s2[0]; pu.u[2] = s1[1]; pu.u[3] = s2[1];
      o0 = __builtin_amdgcn_mfma_f32_32x32x16_bf16(vf[c], pu.v, o0, 0, 0, 0);
      o1 = __builtin_amdgcn_mfma_f32_32x32x16_bf16(vf[4 + c], pu.v, o1, 0, 0, 0);
    }
    __builtin_amdgcn_s_setprio(0);

    if (kt < 14) {
      asm volatile("s_waitcnt vmcnt(2)" ::: "memory");
    } else {
      asm volatile("s_waitcnt vmcnt(0)" ::: "memory");
    }
    __builtin_amdgcn_sched_barrier(0);
    __builtin_amdgcn_s_barrier();

    rd = (rd == 2) ? 0 : rd + 1;
    sb = (sb == 2) ? 0 : sb + 1;
  }

  // ---- epilogue: normalize, transpose O^T -> O via LDS (2 half-passes) ----
  const float inv = 1.f / l_r;
  float* ow = sm.ol[w];
  const int qr = l >> 1, ch = l & 1;
  const float* rp = ow + qr * 34 + ch * 16;
  float* op = out + ((size_t)(b * S_N + qbase + qr) * D_N + h * HD_N + ch * 16);

#pragma unroll
  for (int g = 0; g < 4; ++g) {
    f32x4 v;
#pragma unroll
    for (int j = 0; j < 4; ++j) v[j] = o0[g * 4 + j] * inv;
    *(f32x4*)(ow + ln * 34 + g * 8 + hi * 4) = v;
  }
  asm volatile("s_waitcnt lgkmcnt(0)" ::: "memory");
  __builtin_amdgcn_sched_barrier(0);
#pragma unroll
  for (int j = 0; j < 4; ++j)
    *(f32x4*)(op + j * 4) = *(const f32x4*)(rp + j * 4);
  asm volatile("s_waitcnt lgkmcnt(0)" ::: "memory");
  __builtin_amdgcn_sched_barrier(0);

#pragma unroll
  for (int g = 0; g < 4; ++g) {
    f32x4 v;
#pragma unroll
    for (int j = 0; j < 4; ++j) v[j] = o1[g * 4 + j] * inv;
    *(f32x4*)(ow + ln * 34 + g * 8 + hi * 4) = v;
  }
  asm volatile("s_waitcnt lgkmcnt(0)" ::: "memory");
  __builtin_amdgcn_sched_barrier(0);
#pragma unroll
  for (int j = 0; j < 4; ++j)
    *(f32x4*)(op + 32 + j * 4) = *(const f32x4*)(rp + j * 4);
#undef STAGE
}

// ---------------------------------------------------------------------------
extern "C" void kernel_launch(void* const* d_in, const int* in_sizes, int n_in,
                              void* d_out, int out_size, void* d_ws, size_t ws_size,
                              hipStream_t stream) {
  const float* Qs = (const float*)d_in[0];
  const float* Ks = (const float*)d_in[1];
  const float* Vs = (const float*)d_in[2];
  const float* WQ = (const float*)d_in[3];
  const float* WK = (const float*)d_in[4];
  const float* WV = (const float*)d_in[5];
  if (ws_size < 50331648ull) return;  // Ybf: 3 * 8192*1024 bf16

  u16* Ybf = (u16*)d_ws;
  float* out = (float*)d_out;

  gemm_qkv<<<dim3(768), 512, 0, stream>>>(Qs, Ks, Vs, WQ, WK, WV, Ybf);
  attn_fwd<<<dim3(512), 512, 0, stream>>>(Ybf, Ybf + 8388608, Ybf + 16777216, out);
}

// Round 13
// 142.798 us; speedup vs baseline: 1.1858x; 1.0371x over previous
//
#include <hip/hip_runtime.h>
#include <stdint.h>

// ---------------------------------------------------------------------------
// SelfAttention: B=8,S=1024,D=1024,H=16,HD=64
//   Y{q,k,v} = bf16(X) @ bf16(W)^T (fused fp32->bf16 in staging), then
//   flash attention (swapped QK^T, in-register softmax, O^T accumulation).
// Round 13:
//  - gemm: exact R8 (best measured).
//  - attn: T15 att[2] double-pipeline on the R8 structure. QK^T(kt+1) is
//    issued BEFORE softmax(kt): next tile's MFMAs fill the matrix pipe
//    while this tile's softmax/exp runs on VALU/trans. Quad-buffered K/V
//    (64 KB), stage kt+3 during kt; vmcnt(4) retires kt+2 each iteration
//    (vmcnt(0) from kt=13). Two score states, compile-time swap (x2
//    unroll). 2 blocks/CU.
// ws layout: Ybf only: 3 * 8192*1024 bf16 = 50,331,648 bytes.
// ---------------------------------------------------------------------------

#define B_N 8
#define S_N 1024
#define D_N 1024
#define H_N 16
#define HD_N 64
#define M_N (B_N * S_N) /* 8192 */

typedef __bf16 bfrag __attribute__((ext_vector_type(8)));
typedef float f32x4 __attribute__((ext_vector_type(4)));
typedef float f32x16 __attribute__((ext_vector_type(16)));
typedef unsigned int u32;
typedef u32 u32x2 __attribute__((ext_vector_type(2)));
typedef u32 u32x4 __attribute__((ext_vector_type(4)));
typedef unsigned short u16;

__device__ __forceinline__ u16 f2bf(float f) {  // RNE fp32 -> bf16 bits
  uint32_t u = __float_as_uint(f);
  u += 0x7FFFu + ((u >> 16) & 1u);
  return (u16)(u >> 16);
}

__device__ __forceinline__ void gl_lds16(const void* g, void* l) {
  __builtin_amdgcn_global_load_lds(
      (const __attribute__((address_space(1))) uint32_t*)g,
      (__attribute__((address_space(3))) uint32_t*)l, 16, 0, 0);
}

__device__ __forceinline__ u32 cvtpk(float lo, float hi) {
  u32 r;
  asm("v_cvt_pk_bf16_f32 %0, %1, %2" : "=v"(r) : "v"(lo), "v"(hi));
  return r;
}

__device__ __forceinline__ float exp2r(float x) {  // raw v_exp_f32
#if __has_builtin(__builtin_amdgcn_exp2f)
  return __builtin_amdgcn_exp2f(x);
#else
  float r;
  asm("v_exp_f32 %0, %1" : "=v"(r) : "v"(x));
  return r;
#endif
}

__device__ __forceinline__ u32x2 pl32swap(u32 a, u32 b) {
#if __has_builtin(__builtin_amdgcn_permlane32_swap)
  return __builtin_amdgcn_permlane32_swap(a, b, false, false);
#else
  u32 sa = (u32)__shfl_xor((int)a, 32, 64), sb = (u32)__shfl_xor((int)b, 32, 64);
  const bool hi = (threadIdx.x & 32) != 0;
  u32x2 r;
  r[0] = hi ? sb : a;
  r[1] = hi ? b : sa;
  return r;
#endif
}

__device__ __forceinline__ float xhalf_max(float v) {
  u32x2 r = pl32swap(__float_as_uint(v), __float_as_uint(v));
  return fmaxf(__uint_as_float(r[0]), __uint_as_float(r[1]));
}
__device__ __forceinline__ float xhalf_add(float v) {
  u32x2 r = pl32swap(__float_as_uint(v), __float_as_uint(v));
  return __uint_as_float(r[0]) + __uint_as_float(r[1]);
}

// ---------------- fused projection GEMM: Y = bf16(X) @ bf16(W)^T -----------
// 256x128 tiles, 768 blocks = 3 exact rounds, 8 waves 4Mx2N, 2-buffer LDS.
// Exact R8 schedule (measured best).
__global__ __launch_bounds__(512, 1) void gemm_qkv(
    const float* __restrict__ Qs, const float* __restrict__ Ks,
    const float* __restrict__ Vs, const float* __restrict__ WQ,
    const float* __restrict__ WK, const float* __restrict__ WV,
    u16* __restrict__ Ybf) {
  const int bid = blockIdx.x;
  const int wid = (bid & 7) * 96 + (bid >> 3);  // bijective: 768 % 8 == 0
  const int mat = wid >> 8;                     // 256 tiles per matrix
  const int rem = wid & 255;
  const int m0 = (rem >> 3) * 256;
  const int n0 = (rem & 7) * 128;

  const float* A = mat == 0 ? Qs : (mat == 1 ? Ks : Vs);
  const float* Bw = mat == 0 ? WQ : (mat == 1 ? WK : WV);
  u16* Y = Ybf + (size_t)mat * (M_N * D_N);

  __shared__ u16 Ast[2][4][4096];  // [buf][chunk: 64 rows][64x64], 64 KB
  __shared__ u16 Bst[2][2][4096];  // [buf][chunk: 64 cols][64x64], 32 KB

  const int t = threadIdx.x;
  const int w = t >> 6, l = t & 63;
  const int lr = l & 15, lg = l >> 4;
  const int wm = w >> 1, wn = w & 1;

  const float* aSrc = A + (size_t)(m0 + (t >> 3)) * D_N + (t & 7) * 8;
  const float* bSrc = Bw + (size_t)(n0 + (t >> 3)) * D_N + (t & 7) * 8;
  const int dst8 = (t >> 3) * 64 + ((((t & 7) ^ ((t >> 3) & 7))) << 3);

  const int asw = (lr & 7) << 3;
  const int koff0 = (lg * 8) ^ asw;
  const int koff1 = (32 + lg * 8) ^ asw;

  float4 ra[4][2], rw[2][2];

#define LOADT(tt)                                                             \
  do {                                                                        \
    _Pragma("unroll") for (int c_ = 0; c_ < 4; ++c_) {                        \
      ra[c_][0] = *(const float4*)(aSrc + (size_t)(c_ * 64) * D_N + (tt)*64); \
      ra[c_][1] =                                                             \
          *(const float4*)(aSrc + (size_t)(c_ * 64) * D_N + (tt)*64 + 4);     \
    }                                                                         \
    _Pragma("unroll") for (int c_ = 0; c_ < 2; ++c_) {                        \
      rw[c_][0] = *(const float4*)(bSrc + (size_t)(c_ * 64) * D_N + (tt)*64); \
      rw[c_][1] =                                                             \
          *(const float4*)(bSrc + (size_t)(c_ * 64) * D_N + (tt)*64 + 4);     \
    }                                                                         \
  } while (0)
#define WRITET(buf)                                                           \
  do {                                                                        \
    _Pragma("unroll") for (int c_ = 0; c_ < 4; ++c_) {                        \
      u32x4 pk_;                                                              \
      pk_[0] = cvtpk(ra[c_][0].x, ra[c_][0].y);                               \
      pk_[1] = cvtpk(ra[c_][0].z, ra[c_][0].w);                               \
      pk_[2] = cvtpk(ra[c_][1].x, ra[c_][1].y);                               \
      pk_[3] = cvtpk(ra[c_][1].z, ra[c_][1].w);                               \
      *(u32x4*)(&Ast[buf][c_][dst8]) = pk_;                                   \
    }                                                                         \
    _Pragma("unroll") for (int c_ = 0; c_ < 2; ++c_) {                        \
      u32x4 pk_;                                                              \
      pk_[0] = cvtpk(rw[c_][0].x, rw[c_][0].y);                               \
      pk_[1] = cvtpk(rw[c_][0].z, rw[c_][0].w);                               \
      pk_[2] = cvtpk(rw[c_][1].x, rw[c_][1].y);                               \
      pk_[3] = cvtpk(rw[c_][1].z, rw[c_][1].w);                               \
      *(u32x4*)(&Bst[buf][c_][dst8]) = pk_;                                   \
    }                                                                         \
  } while (0)
#define LDA8(AR, buf)                                                         \
  do {                                                                        \
    const u16* p_ = &Ast[buf][wm][lr * 64];                                   \
    _Pragma("unroll") for (int mf_ = 0; mf_ < 4; ++mf_) {                     \
      AR[mf_][0] = *(const bfrag*)(p_ + mf_ * 1024 + koff0);                  \
      AR[mf_][1] = *(const bfrag*)(p_ + mf_ * 1024 + koff1);                  \
    }                                                                         \
  } while (0)
#define LDB4(BR, buf, h)                                                      \
  do {                                                                        \
    const u16* p_ = &Bst[buf][wn][((h)*32 + lr) * 64];                        \
    BR[0][0] = *(const bfrag*)(p_ + koff0);                                   \
    BR[0][1] = *(const bfrag*)(p_ + koff1);                                   \
    BR[1][0] = *(const bfrag*)(p_ + 1024 + koff0);                            \
    BR[1][1] = *(const bfrag*)(p_ + 1024 + koff1);                            \
  } while (0)
#define MMAH(h, AR, BR)                                                       \
  do {                                                                        \
    __builtin_amdgcn_s_setprio(1);                                            \
    _Pragma("unroll") for (int mf_ = 0; mf_ < 4; ++mf_)                       \
    _Pragma("unroll") for (int j_ = 0; j_ < 2; ++j_)                          \
    _Pragma("unroll") for (int kk_ = 0; kk_ < 2; ++kk_)                       \
      acc[mf_][(h)*2 + j_] = __builtin_amdgcn_mfma_f32_16x16x32_bf16(         \
          AR[mf_][kk_], BR[j_][kk_], acc[mf_][(h)*2 + j_], 0, 0, 0);          \
    __builtin_amdgcn_s_setprio(0);                                            \
  } while (0)
#define BARR()                                                                \
  __builtin_amdgcn_s_barrier();                                               \
  __builtin_amdgcn_sched_barrier(0)
#define WAITL()                                                               \
  asm volatile("s_waitcnt lgkmcnt(0)" ::: "memory");                          \
  __builtin_amdgcn_sched_barrier(0)
#define WAITV0()                                                              \
  asm volatile("s_waitcnt vmcnt(0)" ::: "memory");                            \
  __builtin_amdgcn_sched_barrier(0)

  f32x4 acc[4][4];
#pragma unroll
  for (int i = 0; i < 4; ++i)
#pragma unroll
    for (int j = 0; j < 4; ++j) acc[i][j] = (f32x4){0.f, 0.f, 0.f, 0.f};

  // prologue: tile0 load->write; tile1 loads in flight
  LOADT(0);
  WAITV0();
  WRITET(0);
  LOADT(1);
  WAITL();
  BARR();

  for (int kt = 0; kt < 16; ++kt) {
    const int cb = kt & 1;
    bfrag a[4][2], b[2][2];
    LDA8(a, cb);
    LDB4(b, cb, 0);
    if (kt < 15) {
      WAITV0();          // tile kt+1 loads (issued during kt-1) done
      WRITET(cb ^ 1);    // buffer cb^1 freed by kt-1's end barrier
      if (kt < 14) LOADT(kt + 2);
    }
    WAITL();             // frag reads + ds_writes drained
    MMAH(0, a, b);
    LDB4(b, cb, 1);
    WAITL();
    MMAH(1, a, b);
    BARR();              // publish writes; free buffer cb
  }

  // ---- epilogue ----
  const float alpha = (mat == 0) ? 0.18033688011112042f : 1.0f;
  const int mrow = m0 + wm * 64;
  const int ncol = n0 + wn * 64;
  if (mat < 2) {
#pragma unroll
    for (int mf = 0; mf < 4; ++mf) {
      const int row0 = mrow + mf * 16 + lg * 4;
#pragma unroll
      for (int nf = 0; nf < 4; ++nf) {
        const int col = ncol + nf * 16 + lr;
#pragma unroll
        for (int r = 0; r < 4; ++r)
          Y[(size_t)(row0 + r) * D_N + col] = f2bf(acc[mf][nf][r] * alpha);
      }
    }
  } else {
    const int b = m0 >> 10;
#pragma unroll
    for (int mf = 0; mf < 4; ++mf) {
      const int s0 = (m0 & 1023) + wm * 64 + mf * 16 + lg * 4;
#pragma unroll
      for (int nf = 0; nf < 4; ++nf) {
        const int col = ncol + nf * 16 + lr;
        const f32x4 v = acc[mf][nf];
        ushort4 pk;
        pk.x = f2bf(v[0]); pk.y = f2bf(v[1]);
        pk.z = f2bf(v[2]); pk.w = f2bf(v[3]);
        *(ushort4*)(Y + (size_t)(b * D_N + col) * S_N + s0) = pk;
      }
    }
  }
#undef LOADT
#undef WRITET
#undef LDA8
#undef LDB4
#undef MMAH
#undef BARR
#undef WAITL
#undef WAITV0
}

// ---------------- flash attention: T15 double-pipeline, quad-buffer --------
union AttnSMem {
  struct { u16 K[4][4096]; u16 V[4][4096]; } st;  // 64 KB, quad-buffered
  float ol[4][32 * 34];                           // epilogue transpose (17 KB)
};

__global__ __launch_bounds__(256, 2) void attn_fwd(const u16* __restrict__ Yq,
                                                   const u16* __restrict__ Yk,
                                                   const u16* __restrict__ Yv,
                                                   float* __restrict__ out) {
  // XCD-chunked work id: 1024 blocks, 8 XCDs, 128 consecutive ids per XCD
  const int bid = blockIdx.x;
  const int wid = (bid & 7) * 128 + (bid >> 3);
  const int qt = wid & 7, bh = wid >> 3;
  const int b = bh >> 4, h = bh & 15;
  const int t = threadIdx.x, w = t >> 6, l = t & 63;
  const int ln = l & 31, hi = l >> 5;

  __shared__ AttnSMem sm;

  const int qbase = qt * 128 + w * 32;

  // ---- staging constants (pre-swizzled global source, rule 21) ----
  const int row0 = w * 8 + (l >> 3);
  const int srcoff = (((l & 7) ^ ((l >> 3) & 7)) << 3);
  const u16* kS0 = Yk + ((size_t)(b * S_N + row0) * D_N + h * HD_N + srcoff);
  const u16* vS0 = Yv + ((size_t)(b * D_N + h * HD_N + row0) * S_N + srcoff);

#define STAGE(buf, tt)                                                        \
  do {                                                                        \
    const u16* ka_ = kS0 + (size_t)(tt) * 64 * D_N;                           \
    const u16* va_ = vS0 + (tt) * 64;                                         \
    gl_lds16(ka_, sm.st.K[buf] + w * 512);                                    \
    gl_lds16(ka_ + (size_t)32 * D_N, sm.st.K[buf] + 2048 + w * 512);          \
    gl_lds16(va_, sm.st.V[buf] + w * 512);                                    \
    gl_lds16(va_ + (size_t)32 * S_N, sm.st.V[buf] + 2048 + w * 512);          \
  } while (0)

  // Q loads FIRST (oldest in the vm queue)
  bfrag qf[4];
  {
    const u16* qp = Yq + ((size_t)(b * S_N + qbase + ln) * D_N + h * HD_N + hi * 8);
#pragma unroll
    for (int c = 0; c < 4; ++c) qf[c] = *(const bfrag*)(qp + c * 16);
  }

  // prologue: stage tiles 0, 1, 2 (quad-buffer, 2-deep publish + 1 in flight)
  STAGE(0, 0);
  STAGE(1, 1);
  STAGE(2, 2);

  int kcol[4];
#pragma unroll
  for (int c = 0; c < 4; ++c)
    kcol[c] = (((c * 32 + hi * 16) ^ ((ln & 7) << 4)) >> 1);

  f32x16 o0, o1;
#pragma unroll
  for (int r = 0; r < 16; ++r) { o0[r] = 0.f; o1[r] = 0.f; }
  float m_r = -3.0e38f, l_r = 0.f;

  // retire Q + tile0 + tile1 (leaves tile2's 4 in flight), publish
  asm volatile("s_waitcnt vmcnt(4)" ::: "memory");
  __builtin_amdgcn_sched_barrier(0);
  __builtin_amdgcn_s_barrier();

  // QK^T for tile BUFIDX -> (SA, SB)
#define QKT(BUFIDX, SA, SB)                                                   \
  do {                                                                        \
    const u16* Kb_ = sm.st.K[BUFIDX];                                         \
    bfrag kf_[8];                                                             \
    _Pragma("unroll") for (int s2_ = 0; s2_ < 2; ++s2_)                       \
    _Pragma("unroll") for (int c_ = 0; c_ < 4; ++c_)                          \
      kf_[s2_ * 4 + c_] =                                                     \
          *(const bfrag*)(Kb_ + (s2_ * 32 + ln) * 64 + kcol[c_]);             \
    _Pragma("unroll") for (int r_ = 0; r_ < 16; ++r_) {                       \
      SA[r_] = 0.f; SB[r_] = 0.f;                                             \
    }                                                                         \
    __builtin_amdgcn_s_setprio(1);                                            \
    _Pragma("unroll") for (int c_ = 0; c_ < 4; ++c_) {                        \
      SA = __builtin_amdgcn_mfma_f32_32x32x16_bf16(kf_[c_], qf[c_], SA, 0, 0, 0); \
      SB = __builtin_amdgcn_mfma_f32_32x32x16_bf16(kf_[4 + c_], qf[c_], SB, 0, 0, 0); \
    }                                                                         \
    __builtin_amdgcn_s_setprio(0);                                            \
  } while (0)

  // softmax + P-pack + PV for (SA, SB) with V-buffer VBUF
#define SMPV(SA, SB, VBUF)                                                    \
  do {                                                                        \
    const u16* Vb_ = sm.st.V[VBUF];                                           \
    bfrag vf_[8];                                                             \
    _Pragma("unroll") for (int hf_ = 0; hf_ < 2; ++hf_)                       \
    _Pragma("unroll") for (int c_ = 0; c_ < 4; ++c_)                          \
      vf_[hf_ * 4 + c_] =                                                     \
          *(const bfrag*)(Vb_ + (hf_ * 32 + ln) * 64 + kcol[c_]);             \
    float t16_[16];                                                           \
    _Pragma("unroll") for (int r_ = 0; r_ < 16; ++r_)                         \
        t16_[r_] = fmaxf(SA[r_], SB[r_]);                                     \
    float t8_[8];                                                             \
    _Pragma("unroll") for (int r_ = 0; r_ < 8; ++r_)                          \
        t8_[r_] = fmaxf(t16_[r_], t16_[r_ + 8]);                              \
    float t4_[4];                                                             \
    _Pragma("unroll") for (int r_ = 0; r_ < 4; ++r_)                          \
        t4_[r_] = fmaxf(t8_[r_], t8_[r_ + 4]);                                \
    float pmax_ = fmaxf(fmaxf(t4_[0], t4_[1]), fmaxf(t4_[2], t4_[3]));        \
    pmax_ = xhalf_max(pmax_);                                                 \
    if (__any(pmax_ > m_r + 8.f)) {                                           \
      const float mnew_ = fmaxf(m_r, pmax_);                                  \
      const float corr_ = exp2r(m_r - mnew_);                                 \
      _Pragma("unroll") for (int r_ = 0; r_ < 16; ++r_) {                     \
        o0[r_] *= corr_; o1[r_] *= corr_;                                     \
      }                                                                       \
      l_r *= corr_;                                                           \
      m_r = mnew_;                                                            \
    }                                                                         \
    _Pragma("unroll") for (int r_ = 0; r_ < 16; ++r_)                         \
        SA[r_] = exp2r(SA[r_] - m_r);                                         \
    _Pragma("unroll") for (int r_ = 0; r_ < 16; ++r_)                         \
        SB[r_] = exp2r(SB[r_] - m_r);                                         \
    float s16_[16];                                                           \
    _Pragma("unroll") for (int r_ = 0; r_ < 16; ++r_)                         \
        s16_[r_] = SA[r_] + SB[r_];                                           \
    float s8_[8];                                                             \
    _Pragma("unroll") for (int r_ = 0; r_ < 8; ++r_)                          \
        s8_[r_] = s16_[r_] + s16_[r_ + 8];                                    \
    float s4_[4];                                                             \
    _Pragma("unroll") for (int r_ = 0; r_ < 4; ++r_)                          \
        s4_[r_] = s8_[r_] + s8_[r_ + 4];                                      \
    l_r += xhalf_add((s4_[0] + s4_[1]) + (s4_[2] + s4_[3]));                  \
    __builtin_amdgcn_s_setprio(1);                                            \
    _Pragma("unroll") for (int c_ = 0; c_ < 4; ++c_) {                        \
      const int bs_ = (c_ & 1) * 8;                                           \
      float p0_, p1_, p2_, p3_, p4_, p5_, p6_, p7_;                           \
      if (c_ < 2) {                                                           \
        p0_ = SA[bs_ + 0]; p1_ = SA[bs_ + 1]; p2_ = SA[bs_ + 2];              \
        p3_ = SA[bs_ + 3]; p4_ = SA[bs_ + 4]; p5_ = SA[bs_ + 5];              \
        p6_ = SA[bs_ + 6]; p7_ = SA[bs_ + 7];                                 \
      } else {                                                                \
        p0_ = SB[bs_ + 0]; p1_ = SB[bs_ + 1]; p2_ = SB[bs_ + 2];              \
        p3_ = SB[bs_ + 3]; p4_ = SB[bs_ + 4]; p5_ = SB[bs_ + 5];              \
        p6_ = SB[bs_ + 6]; p7_ = SB[bs_ + 7];                                 \
      }                                                                       \
      const u32 x1_ = cvtpk(p0_, p1_), x2_ = cvtpk(p2_, p3_);                 \
      const u32 y1_ = cvtpk(p4_, p5_), y2_ = cvtpk(p6_, p7_);                 \
      const u32x2 sw1_ = pl32swap(x1_, y1_);                                  \
      const u32x2 sw2_ = pl32swap(x2_, y2_);                                  \
      union { u32 u[4]; bfrag v; } pu_;                                       \
      pu_.u[0] = sw1_[0]; pu_.u[1] = sw2_[0];                                 \
      pu_.u[2] = sw1_[1]; pu_.u[3] = sw2_[1];                                 \
      o0 = __builtin_amdgcn_mfma_f32_32x32x16_bf16(vf_[c_], pu_.v, o0, 0, 0, 0); \
      o1 = __builtin_amdgcn_mfma_f32_32x32x16_bf16(vf_[4 + c_], pu_.v, o1, 0, 0, 0); \
    }                                                                         \
    __builtin_amdgcn_s_setprio(0);                                            \
  } while (0)

  // one pipelined iteration: stage(KT+3), QK^T(KT+1)->OUT, softmax+PV(KT)<-IN
#define ITER(KT, INA, INB, OUTA, OUTB)                                        \
  do {                                                                        \
    if ((KT) < 13) STAGE(((KT) + 3) & 3, (KT) + 3);                           \
    if ((KT) < 15) QKT(((KT) + 1) & 3, OUTA, OUTB);                           \
    SMPV(INA, INB, (KT) & 3);                                                 \
    if ((KT) < 13) {                                                          \
      asm volatile("s_waitcnt vmcnt(4)" ::: "memory");                        \
    } else {                                                                  \
      asm volatile("s_waitcnt vmcnt(0)" ::: "memory");                        \
    }                                                                         \
    __builtin_amdgcn_sched_barrier(0);                                        \
    __builtin_amdgcn_s_barrier();                                             \
  } while (0)

  // prologue: QK^T(0) into the E state
  f32x16 saE, sbE, saO, sbO;
  QKT(0, saE, sbE);

  for (int it = 0; it < 8; ++it) {
    const int kt0 = 2 * it, kt1 = 2 * it + 1;
    ITER(kt0, saE, sbE, saO, sbO);
    ITER(kt1, saO, sbO, saE, sbE);
  }

  // ---- epilogue: normalize, transpose O^T -> O via LDS (2 half-passes) ----
  const float inv = 1.f / l_r;
  float* ow = sm.ol[w];
  const int qr = l >> 1, ch = l & 1;
  const float* rp = ow + qr * 34 + ch * 16;
  float* op = out + ((size_t)(b * S_N + qbase + qr) * D_N + h * HD_N + ch * 16);

#pragma unroll
  for (int g = 0; g < 4; ++g) {
    f32x4 v;
#pragma unroll
    for (int j = 0; j < 4; ++j) v[j] = o0[g * 4 + j] * inv;
    *(f32x4*)(ow + ln * 34 + g * 8 + hi * 4) = v;
  }
  asm volatile("s_waitcnt lgkmcnt(0)" ::: "memory");
  __builtin_amdgcn_sched_barrier(0);
#pragma unroll
  for (int j = 0; j < 4; ++j)
    *(f32x4*)(op + j * 4) = *(const f32x4*)(rp + j * 4);
  asm volatile("s_waitcnt lgkmcnt(0)" ::: "memory");
  __builtin_amdgcn_sched_barrier(0);

#pragma unroll
  for (int g = 0; g < 4; ++g) {
    f32x4 v;
#pragma unroll
    for (int j = 0; j < 4; ++j) v[j] = o1[g * 4 + j] * inv;
    *(f32x4*)(ow + ln * 34 + g * 8 + hi * 4) = v;
  }
  asm volatile("s_waitcnt lgkmcnt(0)" ::: "memory");
  __builtin_amdgcn_sched_barrier(0);
#pragma unroll
  for (int j = 0; j < 4; ++j)
    *(f32x4*)(op + 32 + j * 4) = *(const f32x4*)(rp + j * 4);
#undef STAGE
#undef QKT
#undef SMPV
#undef ITER
}

// ---------------------------------------------------------------------------
extern "C" void kernel_launch(void* const* d_in, const int* in_sizes, int n_in,
                              void* d_out, int out_size, void* d_ws, size_t ws_size,
                              hipStream_t stream) {
  const float* Qs = (const float*)d_in[0];
  const float* Ks = (const float*)d_in[1];
  const float* Vs = (const float*)d_in[2];
  const float* WQ = (const float*)d_in[3];
  const float* WK = (const float*)d_in[4];
  const float* WV = (const float*)d_in[5];
  if (ws_size < 50331648ull) return;  // Ybf: 3 * 8192*1024 bf16

  u16* Ybf = (u16*)d_ws;
  float* out = (float*)d_out;

  gemm_qkv<<<dim3(768), 512, 0, stream>>>(Qs, Ks, Vs, WQ, WK, WV, Ybf);
  attn_fwd<<<dim3(1024), 256, 0, stream>>>(Ybf, Ybf + 8388608, Ybf + 16777216, out);
}

// Round 14
// 136.936 us; speedup vs baseline: 1.2365x; 1.0428x over previous
//
#include <hip/hip_runtime.h>
#include <stdint.h>

// ---------------------------------------------------------------------------
// SelfAttention: B=8,S=1024,D=1024,H=16,HD=64
//   Y{q,k,v} = bf16(X) @ bf16(W)^T (fused fp32->bf16 in staging), then
//   flash attention (swapped QK^T, in-register softmax, O^T accumulation).
// Round 14:
//  - gemm: BK 64->32 at unchanged 256x128 M/N tile. LDS halves to 48 KB ->
//    TWO independent blocks per CU (launch_bounds(512,4)); when one block
//    drains vmcnt/barrier the other fills the pipes (m114). FETCH unchanged
//    (M/N tiling identical -> no R11-style over-fetch). Same R8 schedule,
//    32 K-iterations, same per-tile load count (6 float4/thread).
//  - attn: exact R8 (best measured across R9-R13 experiments).
// ws layout: Ybf only: 3 * 8192*1024 bf16 = 50,331,648 bytes.
// ---------------------------------------------------------------------------

#define B_N 8
#define S_N 1024
#define D_N 1024
#define H_N 16
#define HD_N 64
#define M_N (B_N * S_N) /* 8192 */

typedef __bf16 bfrag __attribute__((ext_vector_type(8)));
typedef float f32x4 __attribute__((ext_vector_type(4)));
typedef float f32x16 __attribute__((ext_vector_type(16)));
typedef unsigned int u32;
typedef u32 u32x2 __attribute__((ext_vector_type(2)));
typedef u32 u32x4 __attribute__((ext_vector_type(4)));
typedef unsigned short u16;

__device__ __forceinline__ u16 f2bf(float f) {  // RNE fp32 -> bf16 bits
  uint32_t u = __float_as_uint(f);
  u += 0x7FFFu + ((u >> 16) & 1u);
  return (u16)(u >> 16);
}

__device__ __forceinline__ void gl_lds16(const void* g, void* l) {
  __builtin_amdgcn_global_load_lds(
      (const __attribute__((address_space(1))) uint32_t*)g,
      (__attribute__((address_space(3))) uint32_t*)l, 16, 0, 0);
}

__device__ __forceinline__ u32 cvtpk(float lo, float hi) {
  u32 r;
  asm("v_cvt_pk_bf16_f32 %0, %1, %2" : "=v"(r) : "v"(lo), "v"(hi));
  return r;
}

__device__ __forceinline__ float exp2r(float x) {  // raw v_exp_f32
#if __has_builtin(__builtin_amdgcn_exp2f)
  return __builtin_amdgcn_exp2f(x);
#else
  float r;
  asm("v_exp_f32 %0, %1" : "=v"(r) : "v"(x));
  return r;
#endif
}

__device__ __forceinline__ u32x2 pl32swap(u32 a, u32 b) {
#if __has_builtin(__builtin_amdgcn_permlane32_swap)
  return __builtin_amdgcn_permlane32_swap(a, b, false, false);
#else
  u32 sa = (u32)__shfl_xor((int)a, 32, 64), sb = (u32)__shfl_xor((int)b, 32, 64);
  const bool hi = (threadIdx.x & 32) != 0;
  u32x2 r;
  r[0] = hi ? sb : a;
  r[1] = hi ? b : sa;
  return r;
#endif
}

__device__ __forceinline__ float xhalf_max(float v) {
  u32x2 r = pl32swap(__float_as_uint(v), __float_as_uint(v));
  return fmaxf(__uint_as_float(r[0]), __uint_as_float(r[1]));
}
__device__ __forceinline__ float xhalf_add(float v) {
  u32x2 r = pl32swap(__float_as_uint(v), __float_as_uint(v));
  return __uint_as_float(r[0]) + __uint_as_float(r[1]);
}

// ---------------- fused projection GEMM: Y = bf16(X) @ bf16(W)^T -----------
// 256x128 tiles, BK=32, 768 blocks, 8 waves 4Mx2N, 2-buffer LDS (48 KB) ->
// 2 blocks/CU. R8 wait schedule over 32 K-iterations.
__global__ __launch_bounds__(512, 4) void gemm_qkv(
    const float* __restrict__ Qs, const float* __restrict__ Ks,
    const float* __restrict__ Vs, const float* __restrict__ WQ,
    const float* __restrict__ WK, const float* __restrict__ WV,
    u16* __restrict__ Ybf) {
  const int bid = blockIdx.x;
  const int wid = (bid & 7) * 96 + (bid >> 3);  // bijective: 768 % 8 == 0
  const int mat = wid >> 8;                     // 256 tiles per matrix
  const int rem = wid & 255;
  const int m0 = (rem >> 3) * 256;
  const int n0 = (rem & 7) * 128;

  const float* A = mat == 0 ? Qs : (mat == 1 ? Ks : Vs);
  const float* Bw = mat == 0 ? WQ : (mat == 1 ? WK : WV);
  u16* Y = Ybf + (size_t)mat * (M_N * D_N);

  __shared__ u16 Ast[2][8192];  // [buf][256 rows x 32 cols bf16], 32 KB
  __shared__ u16 Bst[2][4096];  // [buf][128 rows x 32 cols bf16], 16 KB

  const int t = threadIdx.x;
  const int w = t >> 6, l = t & 63;
  const int lr = l & 15, lg = l >> 4;
  const int wm = w >> 1, wn = w & 1;

  // staging A: thread t owns row t>>1 (0..255), col-half (t&1)*16 fp32.
  const int arow = t >> 1, ahalf = t & 1;
  const float* aSrc = A + (size_t)(m0 + arow) * D_N + ahalf * 16;
  // dest 16B units u = ahalf*2 + {0,1}, swizzled u^(arow&3)
  const int adst0 = arow * 32 + (((ahalf * 2) ^ (arow & 3)) << 3);
  const int adst1 = arow * 32 + (((ahalf * 2 + 1) ^ (arow & 3)) << 3);
  // staging B: thread t owns row t>>2 (0..127), col-quarter (t&3)*8 fp32.
  const int brow = t >> 2, bq = t & 3;
  const float* bSrc = Bw + (size_t)(n0 + brow) * D_N + bq * 8;
  const int bdst = brow * 32 + ((bq ^ (brow & 3)) << 3);

  // swizzled ds_read unit: lg ^ (lr&3)  (row&3 == lr&3 for all fragment rows)
  const int koff = ((lg ^ (lr & 3)) << 3);

  float4 ra[4], rw[2];

#define LOADT(tt)                                                             \
  do {                                                                        \
    const float* pa_ = aSrc + (tt)*32;                                        \
    ra[0] = *(const float4*)(pa_ + 0);                                        \
    ra[1] = *(const float4*)(pa_ + 4);                                        \
    ra[2] = *(const float4*)(pa_ + 8);                                        \
    ra[3] = *(const float4*)(pa_ + 12);                                       \
    const float* pb_ = bSrc + (tt)*32;                                        \
    rw[0] = *(const float4*)(pb_ + 0);                                        \
    rw[1] = *(const float4*)(pb_ + 4);                                        \
  } while (0)
#define WRITET(buf)                                                           \
  do {                                                                        \
    u32x4 p0_, p1_;                                                           \
    p0_[0] = cvtpk(ra[0].x, ra[0].y); p0_[1] = cvtpk(ra[0].z, ra[0].w);       \
    p0_[2] = cvtpk(ra[1].x, ra[1].y); p0_[3] = cvtpk(ra[1].z, ra[1].w);       \
    p1_[0] = cvtpk(ra[2].x, ra[2].y); p1_[1] = cvtpk(ra[2].z, ra[2].w);       \
    p1_[2] = cvtpk(ra[3].x, ra[3].y); p1_[3] = cvtpk(ra[3].z, ra[3].w);       \
    *(u32x4*)(&Ast[buf][adst0]) = p0_;                                        \
    *(u32x4*)(&Ast[buf][adst1]) = p1_;                                        \
    u32x4 pb_;                                                                \
    pb_[0] = cvtpk(rw[0].x, rw[0].y); pb_[1] = cvtpk(rw[0].z, rw[0].w);       \
    pb_[2] = cvtpk(rw[1].x, rw[1].y); pb_[3] = cvtpk(rw[1].z, rw[1].w);       \
    *(u32x4*)(&Bst[buf][bdst]) = pb_;                                         \
  } while (0)
#define LDA4(AR, buf)                                                         \
  do {                                                                        \
    const u16* p_ = &Ast[buf][(wm * 64 + lr) * 32 + koff];                    \
    AR[0] = *(const bfrag*)(p_ + 0 * 512);                                    \
    AR[1] = *(const bfrag*)(p_ + 1 * 512);                                    \
    AR[2] = *(const bfrag*)(p_ + 2 * 512);                                    \
    AR[3] = *(const bfrag*)(p_ + 3 * 512);                                    \
  } while (0)
#define LDB2(BR, buf, h)                                                      \
  do {                                                                        \
    const u16* p_ = &Bst[buf][(wn * 64 + (h)*32 + lr) * 32 + koff];           \
    BR[0] = *(const bfrag*)(p_ + 0 * 512);                                    \
    BR[1] = *(const bfrag*)(p_ + 1 * 512);                                    \
  } while (0)
#define MMAH(h, AR, BR)                                                       \
  do {                                                                        \
    __builtin_amdgcn_s_setprio(1);                                            \
    _Pragma("unroll") for (int mf_ = 0; mf_ < 4; ++mf_)                       \
    _Pragma("unroll") for (int j_ = 0; j_ < 2; ++j_)                          \
      acc[mf_][(h)*2 + j_] = __builtin_amdgcn_mfma_f32_16x16x32_bf16(         \
          AR[mf_], BR[j_], acc[mf_][(h)*2 + j_], 0, 0, 0);                    \
    __builtin_amdgcn_s_setprio(0);                                            \
  } while (0)
#define BARR()                                                                \
  __builtin_amdgcn_s_barrier();                                               \
  __builtin_amdgcn_sched_barrier(0)
#define WAITL()                                                               \
  asm volatile("s_waitcnt lgkmcnt(0)" ::: "memory");                          \
  __builtin_amdgcn_sched_barrier(0)
#define WAITV0()                                                              \
  asm volatile("s_waitcnt vmcnt(0)" ::: "memory");                            \
  __builtin_amdgcn_sched_barrier(0)

  f32x4 acc[4][4];
#pragma unroll
  for (int i = 0; i < 4; ++i)
#pragma unroll
    for (int j = 0; j < 4; ++j) acc[i][j] = (f32x4){0.f, 0.f, 0.f, 0.f};

  // prologue: tile0 load->write; tile1 loads in flight
  LOADT(0);
  WAITV0();
  WRITET(0);
  LOADT(1);
  WAITL();
  BARR();

  for (int kt = 0; kt < 32; ++kt) {
    const int cb = kt & 1;
    bfrag a[4], b[2];
    LDA4(a, cb);
    LDB2(b, cb, 0);
    if (kt < 31) {
      WAITV0();          // tile kt+1 loads (issued during kt-1) done
      WRITET(cb ^ 1);    // buffer cb^1 freed by kt-1's end barrier
      if (kt < 30) LOADT(kt + 2);
    }
    WAITL();             // frag reads + ds_writes drained
    MMAH(0, a, b);
    LDB2(b, cb, 1);
    WAITL();
    MMAH(1, a, b);
    BARR();              // publish writes; free buffer cb
  }

  // ---- epilogue ----
  const float alpha = (mat == 0) ? 0.18033688011112042f : 1.0f;
  const int mrow = m0 + wm * 64;
  const int ncol = n0 + wn * 64;
  if (mat < 2) {
#pragma unroll
    for (int mf = 0; mf < 4; ++mf) {
      const int row0 = mrow + mf * 16 + lg * 4;
#pragma unroll
      for (int nf = 0; nf < 4; ++nf) {
        const int col = ncol + nf * 16 + lr;
#pragma unroll
        for (int r = 0; r < 4; ++r)
          Y[(size_t)(row0 + r) * D_N + col] = f2bf(acc[mf][nf][r] * alpha);
      }
    }
  } else {
    const int b = m0 >> 10;
#pragma unroll
    for (int mf = 0; mf < 4; ++mf) {
      const int s0 = (m0 & 1023) + wm * 64 + mf * 16 + lg * 4;
#pragma unroll
      for (int nf = 0; nf < 4; ++nf) {
        const int col = ncol + nf * 16 + lr;
        const f32x4 v = acc[mf][nf];
        ushort4 pk;
        pk.x = f2bf(v[0]); pk.y = f2bf(v[1]);
        pk.z = f2bf(v[2]); pk.w = f2bf(v[3]);
        *(ushort4*)(Y + (size_t)(b * D_N + col) * S_N + s0) = pk;
      }
    }
  }
#undef LOADT
#undef WRITET
#undef LDA4
#undef LDB2
#undef MMAH
#undef BARR
#undef WAITL
#undef WAITV0
}

// ---------------- flash attention (R8: tri-buffered LDS K/V, vmcnt(4)) -----
union AttnSMem {
  struct { u16 K[3][4096]; u16 V[3][4096]; } st;  // 48 KB, triple-buffered
  float ol[4][32 * 34];                           // epilogue transpose (17 KB)
};

__global__ __launch_bounds__(256, 3) void attn_fwd(const u16* __restrict__ Yq,
                                                   const u16* __restrict__ Yk,
                                                   const u16* __restrict__ Yv,
                                                   float* __restrict__ out) {
  // XCD-chunked work id: 1024 blocks, 8 XCDs, 128 consecutive ids per XCD
  const int bid = blockIdx.x;
  const int wid = (bid & 7) * 128 + (bid >> 3);
  const int qt = wid & 7, bh = wid >> 3;
  const int b = bh >> 4, h = bh & 15;
  const int t = threadIdx.x, w = t >> 6, l = t & 63;
  const int ln = l & 31, hi = l >> 5;

  __shared__ AttnSMem sm;

  const int qbase = qt * 128 + w * 32;

  // ---- staging constants (pre-swizzled global source, rule 21) ----
  const int row0 = w * 8 + (l >> 3);
  const int srcoff = (((l & 7) ^ ((l >> 3) & 7)) << 3);
  const u16* kS0 = Yk + ((size_t)(b * S_N + row0) * D_N + h * HD_N + srcoff);
  const u16* vS0 = Yv + ((size_t)(b * D_N + h * HD_N + row0) * S_N + srcoff);

#define STAGE(buf, tt)                                                        \
  do {                                                                        \
    const u16* ka_ = kS0 + (size_t)(tt) * 64 * D_N;                           \
    const u16* va_ = vS0 + (tt) * 64;                                         \
    gl_lds16(ka_, sm.st.K[buf] + w * 512);                                    \
    gl_lds16(ka_ + (size_t)32 * D_N, sm.st.K[buf] + 2048 + w * 512);          \
    gl_lds16(va_, sm.st.V[buf] + w * 512);                                    \
    gl_lds16(va_ + (size_t)32 * S_N, sm.st.V[buf] + 2048 + w * 512);          \
  } while (0)

  // Q loads FIRST (oldest in the vm queue)
  bfrag qf[4];
  {
    const u16* qp = Yq + ((size_t)(b * S_N + qbase + ln) * D_N + h * HD_N + hi * 8);
#pragma unroll
    for (int c = 0; c < 4; ++c) qf[c] = *(const bfrag*)(qp + c * 16);
  }

  // prologue: stage tiles 0 and 1
  STAGE(0, 0);
  STAGE(1, 1);

  int kcol[4];
#pragma unroll
  for (int c = 0; c < 4; ++c)
    kcol[c] = (((c * 32 + hi * 16) ^ ((ln & 7) << 4)) >> 1);

  f32x16 o0, o1;
#pragma unroll
  for (int r = 0; r < 16; ++r) { o0[r] = 0.f; o1[r] = 0.f; }
  float m_r = -3.0e38f, l_r = 0.f;

  asm volatile("s_waitcnt vmcnt(4)" ::: "memory");
  __builtin_amdgcn_sched_barrier(0);
  __builtin_amdgcn_s_barrier();

  int rd = 0, sb = 2;  // read buffer kt%3; stage buffer (kt+2)%3
  for (int kt = 0; kt < 16; ++kt) {
    if (kt < 14) STAGE(sb, kt + 2);

    const u16* Kb = sm.st.K[rd];
    const u16* Vb = sm.st.V[rd];

    bfrag kf[8];
#pragma unroll
    for (int s2 = 0; s2 < 2; ++s2)
#pragma unroll
      for (int c = 0; c < 4; ++c)
        kf[s2 * 4 + c] = *(const bfrag*)(Kb + (s2 * 32 + ln) * 64 + kcol[c]);

    f32x16 sa, sbv;
#pragma unroll
    for (int r = 0; r < 16; ++r) { sa[r] = 0.f; sbv[r] = 0.f; }
    __builtin_amdgcn_s_setprio(1);
#pragma unroll
    for (int c = 0; c < 4; ++c) {
      sa = __builtin_amdgcn_mfma_f32_32x32x16_bf16(kf[c], qf[c], sa, 0, 0, 0);
      sbv = __builtin_amdgcn_mfma_f32_32x32x16_bf16(kf[4 + c], qf[c], sbv, 0, 0, 0);
    }
    __builtin_amdgcn_s_setprio(0);

    bfrag vf[8];
#pragma unroll
    for (int hf = 0; hf < 2; ++hf)
#pragma unroll
      for (int c = 0; c < 4; ++c)
        vf[hf * 4 + c] = *(const bfrag*)(Vb + (hf * 32 + ln) * 64 + kcol[c]);

    // ---- online softmax, in-lane, tree reductions ----
    float t16[16];
#pragma unroll
    for (int r = 0; r < 16; ++r) t16[r] = fmaxf(sa[r], sbv[r]);
    float t8[8];
#pragma unroll
    for (int r = 0; r < 8; ++r) t8[r] = fmaxf(t16[r], t16[r + 8]);
    float t4[4];
#pragma unroll
    for (int r = 0; r < 4; ++r) t4[r] = fmaxf(t8[r], t8[r + 4]);
    float pmax = fmaxf(fmaxf(t4[0], t4[1]), fmaxf(t4[2], t4[3]));
    pmax = xhalf_max(pmax);

    if (__any(pmax > m_r + 8.f)) {  // defer-max (T13)
      const float mnew = fmaxf(m_r, pmax);
      const float corr = exp2r(m_r - mnew);
#pragma unroll
      for (int r = 0; r < 16; ++r) { o0[r] *= corr; o1[r] *= corr; }
      l_r *= corr;
      m_r = mnew;
    }

#pragma unroll
    for (int r = 0; r < 16; ++r) sa[r] = exp2r(sa[r] - m_r);
#pragma unroll
    for (int r = 0; r < 16; ++r) sbv[r] = exp2r(sbv[r] - m_r);
    float s16[16];
#pragma unroll
    for (int r = 0; r < 16; ++r) s16[r] = sa[r] + sbv[r];
    float s8[8];
#pragma unroll
    for (int r = 0; r < 8; ++r) s8[r] = s16[r] + s16[r + 8];
    float s4[4];
#pragma unroll
    for (int r = 0; r < 4; ++r) s4[r] = s8[r] + s8[r + 4];
    float rsum = (s4[0] + s4[1]) + (s4[2] + s4[3]);
    l_r += xhalf_add(rsum);

    // ---- pack P to bf16 (cvt_pk + permlane32_swap) + PV ----
    __builtin_amdgcn_s_setprio(1);
#pragma unroll
    for (int c = 0; c < 4; ++c) {
      const int bs = (c & 1) * 8;
      float p0, p1, p2, p3, p4, p5, p6, p7;
      if (c < 2) {
        p0 = sa[bs + 0]; p1 = sa[bs + 1]; p2 = sa[bs + 2]; p3 = sa[bs + 3];
        p4 = sa[bs + 4]; p5 = sa[bs + 5]; p6 = sa[bs + 6]; p7 = sa[bs + 7];
      } else {
        p0 = sbv[bs + 0]; p1 = sbv[bs + 1]; p2 = sbv[bs + 2]; p3 = sbv[bs + 3];
        p4 = sbv[bs + 4]; p5 = sbv[bs + 5]; p6 = sbv[bs + 6]; p7 = sbv[bs + 7];
      }
      const u32 x1 = cvtpk(p0, p1), x2 = cvtpk(p2, p3);
      const u32 y1 = cvtpk(p4, p5), y2 = cvtpk(p6, p7);
      const u32x2 s1 = pl32swap(x1, y1);
      const u32x2 s2 = pl32swap(x2, y2);
      union { u32 u[4]; bfrag v; } pu;
      pu.u[0] = s1[0]; pu.u[1] = s2[0]; pu.u[2] = s1[1]; pu.u[3] = s2[1];
      o0 = __builtin_amdgcn_mfma_f32_32x32x16_bf16(vf[c], pu.v, o0, 0, 0, 0);
      o1 = __builtin_amdgcn_mfma_f32_32x32x16_bf16(vf[4 + c], pu.v, o1, 0, 0, 0);
    }
    __builtin_amdgcn_s_setprio(0);

    if (kt < 14) {
      asm volatile("s_waitcnt vmcnt(4)" ::: "memory");
    } else {
      asm volatile("s_waitcnt vmcnt(0)" ::: "memory");
    }
    __builtin_amdgcn_sched_barrier(0);
    __builtin_amdgcn_s_barrier();

    rd = (rd == 2) ? 0 : rd + 1;
    sb = (sb == 2) ? 0 : sb + 1;
  }

  // ---- epilogue: normalize, transpose O^T -> O via LDS (2 half-passes) ----
  const float inv = 1.f / l_r;
  float* ow = sm.ol[w];
  const int qr = l >> 1, ch = l & 1;
  const float* rp = ow + qr * 34 + ch * 16;
  float* op = out + ((size_t)(b * S_N + qbase + qr) * D_N + h * HD_N + ch * 16);

#pragma unroll
  for (int g = 0; g < 4; ++g) {
    f32x4 v;
#pragma unroll
    for (int j = 0; j < 4; ++j) v[j] = o0[g * 4 + j] * inv;
    *(f32x4*)(ow + ln * 34 + g * 8 + hi * 4) = v;
  }
  asm volatile("s_waitcnt lgkmcnt(0)" ::: "memory");
  __builtin_amdgcn_sched_barrier(0);
#pragma unroll
  for (int j = 0; j < 4; ++j)
    *(f32x4*)(op + j * 4) = *(const f32x4*)(rp + j * 4);
  asm volatile("s_waitcnt lgkmcnt(0)" ::: "memory");
  __builtin_amdgcn_sched_barrier(0);

#pragma unroll
  for (int g = 0; g < 4; ++g) {
    f32x4 v;
#pragma unroll
    for (int j = 0; j < 4; ++j) v[j] = o1[g * 4 + j] * inv;
    *(f32x4*)(ow + ln * 34 + g * 8 + hi * 4) = v;
  }
  asm volatile("s_waitcnt lgkmcnt(0)" ::: "memory");
  __builtin_amdgcn_sched_barrier(0);
#pragma unroll
  for (int j = 0; j < 4; ++j)
    *(f32x4*)(op + 32 + j * 4) = *(const f32x4*)(rp + j * 4);
#undef STAGE
}

// ---------------------------------------------------------------------------
extern "C" void kernel_launch(void* const* d_in, const int* in_sizes, int n_in,
                              void* d_out, int out_size, void* d_ws, size_t ws_size,
                              hipStream_t stream) {
  const float* Qs = (const float*)d_in[0];
  const float* Ks = (const float*)d_in[1];
  const float* Vs = (const float*)d_in[2];
  const float* WQ = (const float*)d_in[3];
  const float* WK = (const float*)d_in[4];
  const float* WV = (const float*)d_in[5];
  if (ws_size < 50331648ull) return;  // Ybf: 3 * 8192*1024 bf16

  u16* Ybf = (u16*)d_ws;
  float* out = (float*)d_out;

  gemm_qkv<<<dim3(768), 512, 0, stream>>>(Qs, Ks, Vs, WQ, WK, WV, Ybf);
  attn_fwd<<<dim3(1024), 256, 0, stream>>>(Ybf, Ybf + 8388608, Ybf + 16777216, out);
}

// Round 15
// 135.893 us; speedup vs baseline: 1.2460x; 1.0077x over previous
//
#include <hip/hip_runtime.h>
#include <stdint.h>

// ---------------------------------------------------------------------------
// SelfAttention: B=8,S=1024,D=1024,H=16,HD=64
//   Y{q,k,v} = bf16(X) @ bf16(W)^T (fused fp32->bf16 in staging), then
//   flash attention (swapped QK^T, in-register softmax, O^T accumulation).
// Round 15:
//  - gemm: R14 (BK=32, 48 KB LDS, 2 blocks/CU — first win) with the LDS
//    swizzle fixed from f(row)=row&3 to f(row)=(row>>1)&3. The old XOR used
//    lr&3 which determines the row-parity bank bit -> 16-lane quarters
//    collapsed onto 4 bank-groups (4-way conflict, 9.4M cycles). New f
//    spreads every quarter over 8 groups x 2 lanes = 2-way (free), verified
//    lane-by-lane for A-read/B-read/A-write/B-write.
//  - attn: exact R8 (best measured).
// ws layout: Ybf only: 3 * 8192*1024 bf16 = 50,331,648 bytes.
// ---------------------------------------------------------------------------

#define B_N 8
#define S_N 1024
#define D_N 1024
#define H_N 16
#define HD_N 64
#define M_N (B_N * S_N) /* 8192 */

typedef __bf16 bfrag __attribute__((ext_vector_type(8)));
typedef float f32x4 __attribute__((ext_vector_type(4)));
typedef float f32x16 __attribute__((ext_vector_type(16)));
typedef unsigned int u32;
typedef u32 u32x2 __attribute__((ext_vector_type(2)));
typedef u32 u32x4 __attribute__((ext_vector_type(4)));
typedef unsigned short u16;

__device__ __forceinline__ u16 f2bf(float f) {  // RNE fp32 -> bf16 bits
  uint32_t u = __float_as_uint(f);
  u += 0x7FFFu + ((u >> 16) & 1u);
  return (u16)(u >> 16);
}

__device__ __forceinline__ void gl_lds16(const void* g, void* l) {
  __builtin_amdgcn_global_load_lds(
      (const __attribute__((address_space(1))) uint32_t*)g,
      (__attribute__((address_space(3))) uint32_t*)l, 16, 0, 0);
}

__device__ __forceinline__ u32 cvtpk(float lo, float hi) {
  u32 r;
  asm("v_cvt_pk_bf16_f32 %0, %1, %2" : "=v"(r) : "v"(lo), "v"(hi));
  return r;
}

__device__ __forceinline__ float exp2r(float x) {  // raw v_exp_f32
#if __has_builtin(__builtin_amdgcn_exp2f)
  return __builtin_amdgcn_exp2f(x);
#else
  float r;
  asm("v_exp_f32 %0, %1" : "=v"(r) : "v"(x));
  return r;
#endif
}

__device__ __forceinline__ u32x2 pl32swap(u32 a, u32 b) {
#if __has_builtin(__builtin_amdgcn_permlane32_swap)
  return __builtin_amdgcn_permlane32_swap(a, b, false, false);
#else
  u32 sa = (u32)__shfl_xor((int)a, 32, 64), sb = (u32)__shfl_xor((int)b, 32, 64);
  const bool hi = (threadIdx.x & 32) != 0;
  u32x2 r;
  r[0] = hi ? sb : a;
  r[1] = hi ? b : sa;
  return r;
#endif
}

__device__ __forceinline__ float xhalf_max(float v) {
  u32x2 r = pl32swap(__float_as_uint(v), __float_as_uint(v));
  return fmaxf(__uint_as_float(r[0]), __uint_as_float(r[1]));
}
__device__ __forceinline__ float xhalf_add(float v) {
  u32x2 r = pl32swap(__float_as_uint(v), __float_as_uint(v));
  return __uint_as_float(r[0]) + __uint_as_float(r[1]);
}

// ---------------- fused projection GEMM: Y = bf16(X) @ bf16(W)^T -----------
// 256x128 tiles, BK=32, 768 blocks, 8 waves 4Mx2N, 2-buffer LDS (48 KB) ->
// 2 blocks/CU. R8 wait schedule over 32 K-iterations. f(row)=(row>>1)&3.
__global__ __launch_bounds__(512, 4) void gemm_qkv(
    const float* __restrict__ Qs, const float* __restrict__ Ks,
    const float* __restrict__ Vs, const float* __restrict__ WQ,
    const float* __restrict__ WK, const float* __restrict__ WV,
    u16* __restrict__ Ybf) {
  const int bid = blockIdx.x;
  const int wid = (bid & 7) * 96 + (bid >> 3);  // bijective: 768 % 8 == 0
  const int mat = wid >> 8;                     // 256 tiles per matrix
  const int rem = wid & 255;
  const int m0 = (rem >> 3) * 256;
  const int n0 = (rem & 7) * 128;

  const float* A = mat == 0 ? Qs : (mat == 1 ? Ks : Vs);
  const float* Bw = mat == 0 ? WQ : (mat == 1 ? WK : WV);
  u16* Y = Ybf + (size_t)mat * (M_N * D_N);

  __shared__ u16 Ast[2][8192];  // [buf][256 rows x 32 cols bf16], 32 KB
  __shared__ u16 Bst[2][4096];  // [buf][128 rows x 32 cols bf16], 16 KB

  const int t = threadIdx.x;
  const int w = t >> 6, l = t & 63;
  const int lr = l & 15, lg = l >> 4;
  const int wm = w >> 1, wn = w & 1;

  // staging A: thread t owns row t>>1 (0..255), col-half (t&1)*16 fp32.
  const int arow = t >> 1, ahalf = t & 1;
  const float* aSrc = A + (size_t)(m0 + arow) * D_N + ahalf * 16;
  // dest 16B units u = ahalf*2 + {0,1}, swizzled u^((arow>>1)&3)
  const int afx = (arow >> 1) & 3;
  const int adst0 = arow * 32 + (((ahalf * 2) ^ afx) << 3);
  const int adst1 = arow * 32 + (((ahalf * 2 + 1) ^ afx) << 3);
  // staging B: thread t owns row t>>2 (0..127), col-quarter (t&3)*8 fp32.
  const int brow = t >> 2, bq = t & 3;
  const float* bSrc = Bw + (size_t)(n0 + brow) * D_N + bq * 8;
  const int bdst = brow * 32 + ((bq ^ ((brow >> 1) & 3)) << 3);

  // swizzled ds_read unit: lg ^ ((lr>>1)&3)  ((row>>1)&3 == (lr>>1)&3 for
  // all fragment rows: bases are multiples of 16)
  const int koff = ((lg ^ ((lr >> 1) & 3)) << 3);

  float4 ra[4], rw[2];

#define LOADT(tt)                                                             \
  do {                                                                        \
    const float* pa_ = aSrc + (tt)*32;                                        \
    ra[0] = *(const float4*)(pa_ + 0);                                        \
    ra[1] = *(const float4*)(pa_ + 4);                                        \
    ra[2] = *(const float4*)(pa_ + 8);                                        \
    ra[3] = *(const float4*)(pa_ + 12);                                       \
    const float* pb_ = bSrc + (tt)*32;                                        \
    rw[0] = *(const float4*)(pb_ + 0);                                        \
    rw[1] = *(const float4*)(pb_ + 4);                                        \
  } while (0)
#define WRITET(buf)                                                           \
  do {                                                                        \
    u32x4 p0_, p1_;                                                           \
    p0_[0] = cvtpk(ra[0].x, ra[0].y); p0_[1] = cvtpk(ra[0].z, ra[0].w);       \
    p0_[2] = cvtpk(ra[1].x, ra[1].y); p0_[3] = cvtpk(ra[1].z, ra[1].w);       \
    p1_[0] = cvtpk(ra[2].x, ra[2].y); p1_[1] = cvtpk(ra[2].z, ra[2].w);       \
    p1_[2] = cvtpk(ra[3].x, ra[3].y); p1_[3] = cvtpk(ra[3].z, ra[3].w);       \
    *(u32x4*)(&Ast[buf][adst0]) = p0_;                                        \
    *(u32x4*)(&Ast[buf][adst1]) = p1_;                                        \
    u32x4 pb_;                                                                \
    pb_[0] = cvtpk(rw[0].x, rw[0].y); pb_[1] = cvtpk(rw[0].z, rw[0].w);       \
    pb_[2] = cvtpk(rw[1].x, rw[1].y); pb_[3] = cvtpk(rw[1].z, rw[1].w);       \
    *(u32x4*)(&Bst[buf][bdst]) = pb_;                                         \
  } while (0)
#define LDA4(AR, buf)                                                         \
  do {                                                                        \
    const u16* p_ = &Ast[buf][(wm * 64 + lr) * 32 + koff];                    \
    AR[0] = *(const bfrag*)(p_ + 0 * 512);                                    \
    AR[1] = *(const bfrag*)(p_ + 1 * 512);                                    \
    AR[2] = *(const bfrag*)(p_ + 2 * 512);                                    \
    AR[3] = *(const bfrag*)(p_ + 3 * 512);                                    \
  } while (0)
#define LDB2(BR, buf, h)                                                      \
  do {                                                                        \
    const u16* p_ = &Bst[buf][(wn * 64 + (h)*32 + lr) * 32 + koff];           \
    BR[0] = *(const bfrag*)(p_ + 0 * 512);                                    \
    BR[1] = *(const bfrag*)(p_ + 1 * 512);                                    \
  } while (0)
#define MMAH(h, AR, BR)                                                       \
  do {                                                                        \
    __builtin_amdgcn_s_setprio(1);                                            \
    _Pragma("unroll") for (int mf_ = 0; mf_ < 4; ++mf_)                       \
    _Pragma("unroll") for (int j_ = 0; j_ < 2; ++j_)                          \
      acc[mf_][(h)*2 + j_] = __builtin_amdgcn_mfma_f32_16x16x32_bf16(         \
          AR[mf_], BR[j_], acc[mf_][(h)*2 + j_], 0, 0, 0);                    \
    __builtin_amdgcn_s_setprio(0);                                            \
  } while (0)
#define BARR()                                                                \
  __builtin_amdgcn_s_barrier();                                               \
  __builtin_amdgcn_sched_barrier(0)
#define WAITL()                                                               \
  asm volatile("s_waitcnt lgkmcnt(0)" ::: "memory");                          \
  __builtin_amdgcn_sched_barrier(0)
#define WAITV0()                                                              \
  asm volatile("s_waitcnt vmcnt(0)" ::: "memory");                            \
  __builtin_amdgcn_sched_barrier(0)

  f32x4 acc[4][4];
#pragma unroll
  for (int i = 0; i < 4; ++i)
#pragma unroll
    for (int j = 0; j < 4; ++j) acc[i][j] = (f32x4){0.f, 0.f, 0.f, 0.f};

  // prologue: tile0 load->write; tile1 loads in flight
  LOADT(0);
  WAITV0();
  WRITET(0);
  LOADT(1);
  WAITL();
  BARR();

  for (int kt = 0; kt < 32; ++kt) {
    const int cb = kt & 1;
    bfrag a[4], b[2];
    LDA4(a, cb);
    LDB2(b, cb, 0);
    if (kt < 31) {
      WAITV0();          // tile kt+1 loads (issued during kt-1) done
      WRITET(cb ^ 1);    // buffer cb^1 freed by kt-1's end barrier
      if (kt < 30) LOADT(kt + 2);
    }
    WAITL();             // frag reads + ds_writes drained
    MMAH(0, a, b);
    LDB2(b, cb, 1);
    WAITL();
    MMAH(1, a, b);
    BARR();              // publish writes; free buffer cb
  }

  // ---- epilogue ----
  const float alpha = (mat == 0) ? 0.18033688011112042f : 1.0f;
  const int mrow = m0 + wm * 64;
  const int ncol = n0 + wn * 64;
  if (mat < 2) {
#pragma unroll
    for (int mf = 0; mf < 4; ++mf) {
      const int row0 = mrow + mf * 16 + lg * 4;
#pragma unroll
      for (int nf = 0; nf < 4; ++nf) {
        const int col = ncol + nf * 16 + lr;
#pragma unroll
        for (int r = 0; r < 4; ++r)
          Y[(size_t)(row0 + r) * D_N + col] = f2bf(acc[mf][nf][r] * alpha);
      }
    }
  } else {
    const int b = m0 >> 10;
#pragma unroll
    for (int mf = 0; mf < 4; ++mf) {
      const int s0 = (m0 & 1023) + wm * 64 + mf * 16 + lg * 4;
#pragma unroll
      for (int nf = 0; nf < 4; ++nf) {
        const int col = ncol + nf * 16 + lr;
        const f32x4 v = acc[mf][nf];
        ushort4 pk;
        pk.x = f2bf(v[0]); pk.y = f2bf(v[1]);
        pk.z = f2bf(v[2]); pk.w = f2bf(v[3]);
        *(ushort4*)(Y + (size_t)(b * D_N + col) * S_N + s0) = pk;
      }
    }
  }
#undef LOADT
#undef WRITET
#undef LDA4
#undef LDB2
#undef MMAH
#undef BARR
#undef WAITL
#undef WAITV0
}

// ---------------- flash attention (R8: tri-buffered LDS K/V, vmcnt(4)) -----
union AttnSMem {
  struct { u16 K[3][4096]; u16 V[3][4096]; } st;  // 48 KB, triple-buffered
  float ol[4][32 * 34];                           // epilogue transpose (17 KB)
};

__global__ __launch_bounds__(256, 3) void attn_fwd(const u16* __restrict__ Yq,
                                                   const u16* __restrict__ Yk,
                                                   const u16* __restrict__ Yv,
                                                   float* __restrict__ out) {
  // XCD-chunked work id: 1024 blocks, 8 XCDs, 128 consecutive ids per XCD
  const int bid = blockIdx.x;
  const int wid = (bid & 7) * 128 + (bid >> 3);
  const int qt = wid & 7, bh = wid >> 3;
  const int b = bh >> 4, h = bh & 15;
  const int t = threadIdx.x, w = t >> 6, l = t & 63;
  const int ln = l & 31, hi = l >> 5;

  __shared__ AttnSMem sm;

  const int qbase = qt * 128 + w * 32;

  // ---- staging constants (pre-swizzled global source, rule 21) ----
  const int row0 = w * 8 + (l >> 3);
  const int srcoff = (((l & 7) ^ ((l >> 3) & 7)) << 3);
  const u16* kS0 = Yk + ((size_t)(b * S_N + row0) * D_N + h * HD_N + srcoff);
  const u16* vS0 = Yv + ((size_t)(b * D_N + h * HD_N + row0) * S_N + srcoff);

#define STAGE(buf, tt)                                                        \
  do {                                                                        \
    const u16* ka_ = kS0 + (size_t)(tt) * 64 * D_N;                           \
    const u16* va_ = vS0 + (tt) * 64;                                         \
    gl_lds16(ka_, sm.st.K[buf] + w * 512);                                    \
    gl_lds16(ka_ + (size_t)32 * D_N, sm.st.K[buf] + 2048 + w * 512);          \
    gl_lds16(va_, sm.st.V[buf] + w * 512);                                    \
    gl_lds16(va_ + (size_t)32 * S_N, sm.st.V[buf] + 2048 + w * 512);          \
  } while (0)

  // Q loads FIRST (oldest in the vm queue)
  bfrag qf[4];
  {
    const u16* qp = Yq + ((size_t)(b * S_N + qbase + ln) * D_N + h * HD_N + hi * 8);
#pragma unroll
    for (int c = 0; c < 4; ++c) qf[c] = *(const bfrag*)(qp + c * 16);
  }

  // prologue: stage tiles 0 and 1
  STAGE(0, 0);
  STAGE(1, 1);

  int kcol[4];
#pragma unroll
  for (int c = 0; c < 4; ++c)
    kcol[c] = (((c * 32 + hi * 16) ^ ((ln & 7) << 4)) >> 1);

  f32x16 o0, o1;
#pragma unroll
  for (int r = 0; r < 16; ++r) { o0[r] = 0.f; o1[r] = 0.f; }
  float m_r = -3.0e38f, l_r = 0.f;

  asm volatile("s_waitcnt vmcnt(4)" ::: "memory");
  __builtin_amdgcn_sched_barrier(0);
  __builtin_amdgcn_s_barrier();

  int rd = 0, sb = 2;  // read buffer kt%3; stage buffer (kt+2)%3
  for (int kt = 0; kt < 16; ++kt) {
    if (kt < 14) STAGE(sb, kt + 2);

    const u16* Kb = sm.st.K[rd];
    const u16* Vb = sm.st.V[rd];

    bfrag kf[8];
#pragma unroll
    for (int s2 = 0; s2 < 2; ++s2)
#pragma unroll
      for (int c = 0; c < 4; ++c)
        kf[s2 * 4 + c] = *(const bfrag*)(Kb + (s2 * 32 + ln) * 64 + kcol[c]);

    f32x16 sa, sbv;
#pragma unroll
    for (int r = 0; r < 16; ++r) { sa[r] = 0.f; sbv[r] = 0.f; }
    __builtin_amdgcn_s_setprio(1);
#pragma unroll
    for (int c = 0; c < 4; ++c) {
      sa = __builtin_amdgcn_mfma_f32_32x32x16_bf16(kf[c], qf[c], sa, 0, 0, 0);
      sbv = __builtin_amdgcn_mfma_f32_32x32x16_bf16(kf[4 + c], qf[c], sbv, 0, 0, 0);
    }
    __builtin_amdgcn_s_setprio(0);

    bfrag vf[8];
#pragma unroll
    for (int hf = 0; hf < 2; ++hf)
#pragma unroll
      for (int c = 0; c < 4; ++c)
        vf[hf * 4 + c] = *(const bfrag*)(Vb + (hf * 32 + ln) * 64 + kcol[c]);

    // ---- online softmax, in-lane, tree reductions ----
    float t16[16];
#pragma unroll
    for (int r = 0; r < 16; ++r) t16[r] = fmaxf(sa[r], sbv[r]);
    float t8[8];
#pragma unroll
    for (int r = 0; r < 8; ++r) t8[r] = fmaxf(t16[r], t16[r + 8]);
    float t4[4];
#pragma unroll
    for (int r = 0; r < 4; ++r) t4[r] = fmaxf(t8[r], t8[r + 4]);
    float pmax = fmaxf(fmaxf(t4[0], t4[1]), fmaxf(t4[2], t4[3]));
    pmax = xhalf_max(pmax);

    if (__any(pmax > m_r + 8.f)) {  // defer-max (T13)
      const float mnew = fmaxf(m_r, pmax);
      const float corr = exp2r(m_r - mnew);
#pragma unroll
      for (int r = 0; r < 16; ++r) { o0[r] *= corr; o1[r] *= corr; }
      l_r *= corr;
      m_r = mnew;
    }

#pragma unroll
    for (int r = 0; r < 16; ++r) sa[r] = exp2r(sa[r] - m_r);
#pragma unroll
    for (int r = 0; r < 16; ++r) sbv[r] = exp2r(sbv[r] - m_r);
    float s16[16];
#pragma unroll
    for (int r = 0; r < 16; ++r) s16[r] = sa[r] + sbv[r];
    float s8[8];
#pragma unroll
    for (int r = 0; r < 8; ++r) s8[r] = s16[r] + s16[r + 8];
    float s4[4];
#pragma unroll
    for (int r = 0; r < 4; ++r) s4[r] = s8[r] + s8[r + 4];
    float rsum = (s4[0] + s4[1]) + (s4[2] + s4[3]);
    l_r += xhalf_add(rsum);

    // ---- pack P to bf16 (cvt_pk + permlane32_swap) + PV ----
    __builtin_amdgcn_s_setprio(1);
#pragma unroll
    for (int c = 0; c < 4; ++c) {
      const int bs = (c & 1) * 8;
      float p0, p1, p2, p3, p4, p5, p6, p7;
      if (c < 2) {
        p0 = sa[bs + 0]; p1 = sa[bs + 1]; p2 = sa[bs + 2]; p3 = sa[bs + 3];
        p4 = sa[bs + 4]; p5 = sa[bs + 5]; p6 = sa[bs + 6]; p7 = sa[bs + 7];
      } else {
        p0 = sbv[bs + 0]; p1 = sbv[bs + 1]; p2 = sbv[bs + 2]; p3 = sbv[bs + 3];
        p4 = sbv[bs + 4]; p5 = sbv[bs + 5]; p6 = sbv[bs + 6]; p7 = sbv[bs + 7];
      }
      const u32 x1 = cvtpk(p0, p1), x2 = cvtpk(p2, p3);
      const u32 y1 = cvtpk(p4, p5), y2 = cvtpk(p6, p7);
      const u32x2 s1 = pl32swap(x1, y1);
      const u32x2 s2 = pl32swap(x2, y2);
      union { u32 u[4]; bfrag v; } pu;
      pu.u[0] = s1[0]; pu.u[1] = s2[0]; pu.u[2] = s1[1]; pu.u[3] = s2[1];
      o0 = __builtin_amdgcn_mfma_f32_32x32x16_bf16(vf[c], pu.v, o0, 0, 0, 0);
      o1 = __builtin_amdgcn_mfma_f32_32x32x16_bf16(vf[4 + c], pu.v, o1, 0, 0, 0);
    }
    __builtin_amdgcn_s_setprio(0);

    if (kt < 14) {
      asm volatile("s_waitcnt vmcnt(4)" ::: "memory");
    } else {
      asm volatile("s_waitcnt vmcnt(0)" ::: "memory");
    }
    __builtin_amdgcn_sched_barrier(0);
    __builtin_amdgcn_s_barrier();

    rd = (rd == 2) ? 0 : rd + 1;
    sb = (sb == 2) ? 0 : sb + 1;
  }

  // ---- epilogue: normalize, transpose O^T -> O via LDS (2 half-passes) ----
  const float inv = 1.f / l_r;
  float* ow = sm.ol[w];
  const int qr = l >> 1, ch = l & 1;
  const float* rp = ow + qr * 34 + ch * 16;
  float* op = out + ((size_t)(b * S_N + qbase + qr) * D_N + h * HD_N + ch * 16);

#pragma unroll
  for (int g = 0; g < 4; ++g) {
    f32x4 v;
#pragma unroll
    for (int j = 0; j < 4; ++j) v[j] = o0[g * 4 + j] * inv;
    *(f32x4*)(ow + ln * 34 + g * 8 + hi * 4) = v;
  }
  asm volatile("s_waitcnt lgkmcnt(0)" ::: "memory");
  __builtin_amdgcn_sched_barrier(0);
#pragma unroll
  for (int j = 0; j < 4; ++j)
    *(f32x4*)(op + j * 4) = *(const f32x4*)(rp + j * 4);
  asm volatile("s_waitcnt lgkmcnt(0)" ::: "memory");
  __builtin_amdgcn_sched_barrier(0);

#pragma unroll
  for (int g = 0; g < 4; ++g) {
    f32x4 v;
#pragma unroll
    for (int j = 0; j < 4; ++j) v[j] = o1[g * 4 + j] * inv;
    *(f32x4*)(ow + ln * 34 + g * 8 + hi * 4) = v;
  }
  asm volatile("s_waitcnt lgkmcnt(0)" ::: "memory");
  __builtin_amdgcn_sched_barrier(0);
#pragma unroll
  for (int j = 0; j < 4; ++j)
    *(f32x4*)(op + 32 + j * 4) = *(const f32x4*)(rp + j * 4);
#undef STAGE
}

// ---------------------------------------------------------------------------
extern "C" void kernel_launch(void* const* d_in, const int* in_sizes, int n_in,
                              void* d_out, int out_size, void* d_ws, size_t ws_size,
                              hipStream_t stream) {
  const float* Qs = (const float*)d_in[0];
  const float* Ks = (const float*)d_in[1];
  const float* Vs = (const float*)d_in[2];
  const float* WQ = (const float*)d_in[3];
  const float* WK = (const float*)d_in[4];
  const float* WV = (const float*)d_in[5];
  if (ws_size < 50331648ull) return;  // Ybf: 3 * 8192*1024 bf16

  u16* Ybf = (u16*)d_ws;
  float* out = (float*)d_out;

  gemm_qkv<<<dim3(768), 512, 0, stream>>>(Qs, Ks, Vs, WQ, WK, WV, Ybf);
  attn_fwd<<<dim3(1024), 256, 0, stream>>>(Ybf, Ybf + 8388608, Ybf + 16777216, out);
}